// Round 19
// baseline (160.781 us; speedup 1.0000x reference)
//
#include <hip/hip_runtime.h>

// ---------------------------------------------------------------------------
// Fused attention block: qkv GEMM -> RoPE -> causal SDPA (MFMA) -> out GEMM
// B=2 S=2048 D=1024 H=16 DH=64. bf16 MFMA everywhere.
// MFMA fragment mapping (verified r1-r13): A/B-frag outer=lane&15, k=oct*8+e;
// C/D row=oct*4+r, col=lane&15.
// r19: re-land strip attention (2x16-row strips/wave, K/V frags read once per
//      36 MFMAs -> LDS traffic halved) with ZERO lambdas: attn_tile_step AND
//      attn_write_out are __forceinline__ free functions (r15-r17 spilled via
//      the outlined write_out lambda whose by-ref captures forced acc/accl to
//      scratch). Algorithm byte-equal to correctness-proven r15.
//      gemm_wide/gemm2_ring/prep/trig unchanged from r18.
// ---------------------------------------------------------------------------

typedef __bf16 bf16x8 __attribute__((ext_vector_type(8)));
typedef float f32x4 __attribute__((ext_vector_type(4)));

__device__ __forceinline__ unsigned short f2b(float f) {
  unsigned int u = __builtin_bit_cast(unsigned int, f);
  unsigned int lsb = (u >> 16) & 1u;
  u += 0x7fffu + lsb;  // round-to-nearest-even
  return (unsigned short)(u >> 16);
}
__device__ __forceinline__ float b2f(unsigned short h) {
  unsigned int u = ((unsigned int)h) << 16;
  return __builtin_bit_cast(float, u);
}
__device__ __forceinline__ unsigned int pk2(float a, float b) {
  return (unsigned int)f2b(a) | ((unsigned int)f2b(b) << 16);
}
__device__ __forceinline__ unsigned int cvtpk(float lo, float hi) {
  unsigned int r;
  asm("v_cvt_pk_bf16_f32 %0, %1, %2" : "=v"(r) : "v"(lo), "v"(hi));
  return r;
}
__device__ __forceinline__ void unp8(uint4 v, float* f) {
  unsigned int u[4] = {v.x, v.y, v.z, v.w};
#pragma unroll
  for (int i = 0; i < 4; ++i) {
    f[2 * i] = b2f((unsigned short)(u[i] & 0xffff));
    f[2 * i + 1] = b2f((unsigned short)(u[i] >> 16));
  }
}
__device__ __forceinline__ void gload16(const void* g, void* l) {
  __builtin_amdgcn_global_load_lds(
      (const __attribute__((address_space(1))) unsigned int*)g,
      (__attribute__((address_space(3))) unsigned int*)l, 16, 0, 0);
}

// --------------------------- fp32 -> bf16 convert ---------------------------
__global__ __launch_bounds__(256) void convert_bf16(const float* __restrict__ src,
                                                    unsigned short* __restrict__ dst,
                                                    int n) {
  int i = (blockIdx.x * 256 + threadIdx.x) * 4;
  if (i + 3 < n) {
    float4 v = *(const float4*)&src[i];
    ushort4 o;
    o.x = f2b(v.x); o.y = f2b(v.y); o.z = f2b(v.z); o.w = f2b(v.w);
    *(ushort4*)&dst[i] = o;
  }
}

// ------------------- cos/sin table: computed once, not 32x ------------------
__global__ __launch_bounds__(256) void trig_kernel(const float* __restrict__ freqs,
                                                   float* __restrict__ cosT,
                                                   float* __restrict__ sinT,
                                                   int n) {
  int i = blockIdx.x * 256 + threadIdx.x;
  if (i < n) {
    float f = freqs[i];
    cosT[i] = cosf(f);
    sinT[i] = sinf(f);
  }
}

// -------------------- transpose [K][N] f32 -> [N][K] bf16 -------------------
__global__ __launch_bounds__(256) void transpose_f32_bf16(const float* __restrict__ src,
                                                          unsigned short* __restrict__ dst,
                                                          int K, int N) {
  __shared__ float tile[32][33];
  int n0 = blockIdx.x * 32, k0 = blockIdx.y * 32;
  int c = threadIdx.x & 31, r4 = threadIdx.x >> 5;
#pragma unroll
  for (int p = 0; p < 4; ++p) {
    int r = r4 + p * 8;
    tile[r][c] = src[(size_t)(k0 + r) * N + n0 + c];
  }
  __syncthreads();
#pragma unroll
  for (int p = 0; p < 4; ++p) {
    int r = r4 + p * 8;
    dst[(size_t)(n0 + r) * K + k0 + c] = f2b(tile[c][r]);
  }
}

// ------------- wide-grid ring-buffered bf16 GEMM (for qkv GEMM) ------------
// 128x192 tile, BK=32, 256 thr = 4 waves (2M x 2N), per-wave 64x96 (acc 4x6).
// Ring of 4 LDS slots (20 KB) = 80 KB -> 2 blocks/CU; grid (16,32) = 512
// blocks. Counted vmcnt(10); epilogue ladder 10/5/0.
__global__ __launch_bounds__(256, 2) void gemm_wide(const unsigned short* __restrict__ A,
                                                    const unsigned short* __restrict__ BT,
                                                    unsigned short* __restrict__ C,
                                                    int M, int N, int K) {
  extern __shared__ unsigned short L[];  // 4 slots x 10240 ushort = 80 KB
  const int tid = threadIdx.x, lane = tid & 63, w = tid >> 6;
  const int wr = w >> 1, wc = w & 1;
  const int fr = lane & 15, oct = lane >> 4;

  const int m0 = blockIdx.y * 128, n0 = blockIdx.x * 192;

  const int sr = tid >> 2;                                 // 0..63
  const int scol = ((tid & 3) ^ ((tid >> 3) & 3)) * 8;     // swizzled src col
  const size_t aR0 = (size_t)(m0 + sr) * K + scol;
  const size_t aR1 = (size_t)(m0 + 64 + sr) * K + scol;
  const size_t bR0 = (size_t)(n0 + sr) * K + scol;
  const size_t bR1 = (size_t)(n0 + 64 + sr) * K + scol;
  const size_t bR2 = (size_t)(n0 + 128 + sr) * K + scol;

  f32x4 acc[4][6] = {};
  const int T = K >> 5;

  for (int pt = 0; pt < 3; ++pt) {  // prologue: stage tiles 0,1,2
    unsigned short* Ln = &L[pt * 10240];
    const size_t gk = (size_t)pt * 32;
    gload16(&A[aR0 + gk], &Ln[tid * 8]);
    gload16(&A[aR1 + gk], &Ln[2048 + tid * 8]);
    gload16(&BT[bR0 + gk], &Ln[4096 + tid * 8]);
    gload16(&BT[bR1 + gk], &Ln[6144 + tid * 8]);
    gload16(&BT[bR2 + gk], &Ln[8192 + tid * 8]);
  }

  for (int t = 0; t < T; ++t) {
    if (t + 3 <= T) {
      asm volatile("s_waitcnt vmcnt(10)" ::: "memory");
    } else if (t + 2 == T) {
      asm volatile("s_waitcnt vmcnt(5)" ::: "memory");
    } else {
      asm volatile("s_waitcnt vmcnt(0)" ::: "memory");
    }
    __builtin_amdgcn_sched_barrier(0);
    __builtin_amdgcn_s_barrier();
    __builtin_amdgcn_sched_barrier(0);

    const unsigned short* Lb = &L[(t & 3) * 10240];
    unsigned short* Ln = &L[((t + 3) & 3) * 10240];
    const size_t gk = (size_t)(t + 3) * 32;
    const bool doStage = (t + 3 < T);

    bf16x8 af[4], bf[6];
#pragma unroll
    for (int i = 0; i < 4; ++i) {
      const int ra = wr * 64 + i * 16 + fr;
      af[i] = __builtin_bit_cast(
          bf16x8, *(const uint4*)&Lb[ra * 32 + ((oct ^ ((ra >> 1) & 3)) * 8)]);
    }
#pragma unroll
    for (int j = 0; j < 3; ++j) {
      const int rb = wc * 96 + j * 16 + fr;
      bf[j] = __builtin_bit_cast(
          bf16x8,
          *(const uint4*)&Lb[4096 + rb * 32 + ((oct ^ ((rb >> 1) & 3)) * 8)]);
    }
    if (doStage) {
      gload16(&A[aR0 + gk], &Ln[tid * 8]);
      gload16(&A[aR1 + gk], &Ln[2048 + tid * 8]);
      gload16(&BT[bR0 + gk], &Ln[4096 + tid * 8]);
    }
    __builtin_amdgcn_s_setprio(1);
#pragma unroll
    for (int i = 0; i < 4; ++i)
#pragma unroll
      for (int j = 0; j < 3; ++j)
        acc[i][j] = __builtin_amdgcn_mfma_f32_16x16x32_bf16(af[i], bf[j], acc[i][j], 0, 0, 0);
    __builtin_amdgcn_s_setprio(0);

#pragma unroll
    for (int j = 3; j < 6; ++j) {
      const int rb = wc * 96 + j * 16 + fr;
      bf[j] = __builtin_bit_cast(
          bf16x8,
          *(const uint4*)&Lb[4096 + rb * 32 + ((oct ^ ((rb >> 1) & 3)) * 8)]);
    }
    if (doStage) {
      gload16(&BT[bR1 + gk], &Ln[6144 + tid * 8]);
      gload16(&BT[bR2 + gk], &Ln[8192 + tid * 8]);
    }
    __builtin_amdgcn_s_setprio(1);
#pragma unroll
    for (int i = 0; i < 4; ++i)
#pragma unroll
      for (int j = 3; j < 6; ++j)
        acc[i][j] = __builtin_amdgcn_mfma_f32_16x16x32_bf16(af[i], bf[j], acc[i][j], 0, 0, 0);
    __builtin_amdgcn_s_setprio(0);
  }

#pragma unroll
  for (int i = 0; i < 4; ++i)
#pragma unroll
    for (int j = 0; j < 6; ++j)
#pragma unroll
      for (int r = 0; r < 4; ++r)
        C[(size_t)(m0 + wr * 64 + i * 16 + oct * 4 + r) * N + n0 + wc * 96 +
          j * 16 + fr] = f2b(acc[i][j][r]);
}

// ---------------- ring-buffered bf16 GEMM for out GEMM (f32 C) -------------
// 128x64 tile, BK=32, 256 thr = 4 waves (2M x 2N), per-wave 64x32 (acc 4x2).
// Ring of 4 LDS slots (12 KB) = 48 KB -> 2 blocks/CU; grid (16,32) = 512
// blocks. 3 stage-issues/tile; counted vmcnt(6); epilogue ladder 6/3/0.
__global__ __launch_bounds__(256, 2) void gemm2_ring(const unsigned short* __restrict__ A,
                                                     const unsigned short* __restrict__ BT,
                                                     float* __restrict__ C,
                                                     int M, int N, int K) {
  extern __shared__ unsigned short L[];  // 4 slots x 6144 ushort = 48 KB
  const int tid = threadIdx.x, lane = tid & 63, w = tid >> 6;
  const int wr = w >> 1, wc = w & 1;
  const int fr = lane & 15, oct = lane >> 4;
  const int m0 = blockIdx.y * 128, n0 = blockIdx.x * 64;

  const int sr = tid >> 2;
  const int scol = ((tid & 3) ^ ((tid >> 3) & 3)) * 8;  // swizzled src col
  const size_t aR0 = (size_t)(m0 + sr) * K + scol;
  const size_t aR1 = (size_t)(m0 + 64 + sr) * K + scol;
  const size_t bR0 = (size_t)(n0 + sr) * K + scol;

  f32x4 acc[4][2] = {};
  const int T = K >> 5;

  for (int pt = 0; pt < 3; ++pt) {  // prologue: stage tiles 0,1,2
    unsigned short* Ln = &L[pt * 6144];
    const size_t gk = (size_t)pt * 32;
    gload16(&A[aR0 + gk], &Ln[tid * 8]);
    gload16(&A[aR1 + gk], &Ln[2048 + tid * 8]);
    gload16(&BT[bR0 + gk], &Ln[4096 + tid * 8]);
  }

  for (int t = 0; t < T; ++t) {
    if (t + 3 <= T) {
      asm volatile("s_waitcnt vmcnt(6)" ::: "memory");
    } else if (t + 2 == T) {
      asm volatile("s_waitcnt vmcnt(3)" ::: "memory");
    } else {
      asm volatile("s_waitcnt vmcnt(0)" ::: "memory");
    }
    __builtin_amdgcn_sched_barrier(0);
    __builtin_amdgcn_s_barrier();
    __builtin_amdgcn_sched_barrier(0);

    const unsigned short* Lb = &L[(t & 3) * 6144];
    unsigned short* Ln = &L[((t + 3) & 3) * 6144];
    const size_t gk = (size_t)(t + 3) * 32;
    const bool doStage = (t + 3 < T);

    bf16x8 af[4], bq[2];
#pragma unroll
    for (int i = 0; i < 4; ++i) {
      const int ra = wr * 64 + i * 16 + fr;
      af[i] = __builtin_bit_cast(
          bf16x8, *(const uint4*)&Lb[ra * 32 + ((oct ^ ((ra >> 1) & 3)) * 8)]);
    }
#pragma unroll
    for (int j = 0; j < 2; ++j) {
      const int rb = wc * 32 + j * 16 + fr;
      bq[j] = __builtin_bit_cast(
          bf16x8,
          *(const uint4*)&Lb[4096 + rb * 32 + ((oct ^ ((rb >> 1) & 3)) * 8)]);
    }
    if (doStage) {
      gload16(&A[aR0 + gk], &Ln[tid * 8]);
      gload16(&A[aR1 + gk], &Ln[2048 + tid * 8]);
      gload16(&BT[bR0 + gk], &Ln[4096 + tid * 8]);
    }
    __builtin_amdgcn_s_setprio(1);
#pragma unroll
    for (int i = 0; i < 4; ++i)
#pragma unroll
      for (int j = 0; j < 2; ++j)
        acc[i][j] = __builtin_amdgcn_mfma_f32_16x16x32_bf16(af[i], bq[j], acc[i][j], 0, 0, 0);
    __builtin_amdgcn_s_setprio(0);
  }

#pragma unroll
  for (int i = 0; i < 4; ++i)
#pragma unroll
    for (int j = 0; j < 2; ++j)
#pragma unroll
      for (int r = 0; r < 4; ++r)
        C[(size_t)(m0 + wr * 64 + i * 16 + oct * 4 + r) * N + n0 + wc * 32 +
          j * 16 + fr] = acc[i][j][r];
}

// ----------------- prep: RoPE + layout (Q,K rows; V tile-blocked+permuted) --
__global__ __launch_bounds__(256) void prep_kernel(const unsigned short* __restrict__ qkvb,
                                                   const float* __restrict__ cosT,
                                                   const float* __restrict__ sinT,
                                                   unsigned short* __restrict__ Qb,
                                                   unsigned short* __restrict__ Kb,
                                                   unsigned short* __restrict__ Vtg) {
  const int sb = blockIdx.x, h = blockIdx.y, b = blockIdx.z;
  const int tid = threadIdx.x;
  __shared__ float Vs[64][65];
  const int sl = tid >> 2, c8 = (tid & 3) * 8;
  const int s = sb * 64 + sl;
  const size_t tok = (size_t)(b * 2048 + s);
  const unsigned short* row = qkvb + tok * 3072 + h * 64;
  const float QSCALE = 0.125f * 1.44269504f;

  float cl[8], snl[8], ch[8], snh[8];
  {
    const float* cb = cosT + s * 64;
    const float* sbp = sinT + s * 64;
    *(float4*)&cl[0] = *(const float4*)&cb[c8];
    *(float4*)&cl[4] = *(const float4*)&cb[c8 + 4];
    *(float4*)&ch[0] = *(const float4*)&cb[32 + c8];
    *(float4*)&ch[4] = *(const float4*)&cb[32 + c8 + 4];
    *(float4*)&snl[0] = *(const float4*)&sbp[c8];
    *(float4*)&snl[4] = *(const float4*)&sbp[c8 + 4];
    *(float4*)&snh[0] = *(const float4*)&sbp[32 + c8];
    *(float4*)&snh[4] = *(const float4*)&sbp[32 + c8 + 4];
  }
  const size_t obase = ((size_t)(b * 16 + h) * 2048 + s) * 64;

  // Q (scaled)
  {
    float lo[8], hi[8];
    unp8(*(const uint4*)(row + c8), lo);
    unp8(*(const uint4*)(row + 32 + c8), hi);
    float olo[8], ohi[8];
#pragma unroll
    for (int e = 0; e < 8; ++e) {
      olo[e] = (lo[e] * cl[e] - hi[e] * snl[e]) * QSCALE;
      ohi[e] = (hi[e] * ch[e] + lo[e] * snh[e]) * QSCALE;
    }
    uint4 w0, w1;
    w0.x = pk2(olo[0], olo[1]); w0.y = pk2(olo[2], olo[3]);
    w0.z = pk2(olo[4], olo[5]); w0.w = pk2(olo[6], olo[7]);
    w1.x = pk2(ohi[0], ohi[1]); w1.y = pk2(ohi[2], ohi[3]);
    w1.z = pk2(ohi[4], ohi[5]); w1.w = pk2(ohi[6], ohi[7]);
    *(uint4*)(Qb + obase + c8) = w0;
    *(uint4*)(Qb + obase + 32 + c8) = w1;
  }
  // K
  {
    float lo[8], hi[8];
    unp8(*(const uint4*)(row + 1024 + c8), lo);
    unp8(*(const uint4*)(row + 1024 + 32 + c8), hi);
    float olo[8], ohi[8];
#pragma unroll
    for (int e = 0; e < 8; ++e) {
      olo[e] = lo[e] * cl[e] - hi[e] * snl[e];
      ohi[e] = hi[e] * ch[e] + lo[e] * snh[e];
    }
    uint4 w0, w1;
    w0.x = pk2(olo[0], olo[1]); w0.y = pk2(olo[2], olo[3]);
    w0.z = pk2(olo[4], olo[5]); w0.w = pk2(olo[6], olo[7]);
    w1.x = pk2(ohi[0], ohi[1]); w1.y = pk2(ohi[2], ohi[3]);
    w1.z = pk2(ohi[4], ohi[5]); w1.w = pk2(ohi[6], ohi[7]);
    *(uint4*)(Kb + obase + c8) = w0;
    *(uint4*)(Kb + obase + 32 + c8) = w1;
  }
  // V -> LDS f32, then tile-blocked + k-permuted bf16 out
  {
    float lo[8], hi[8];
    unp8(*(const uint4*)(row + 2048 + c8), lo);
    unp8(*(const uint4*)(row + 2048 + 32 + c8), hi);
#pragma unroll
    for (int e = 0; e < 8; ++e) {
      Vs[sl][c8 + e] = lo[e];
      Vs[sl][32 + c8 + e] = hi[e];
    }
  }
  __syncthreads();
  {
    const int d = tid >> 2, q2 = tid & 3;
    const int m = q2 >> 1, tp = q2 & 1;
    const int sc0 = q2 * 16;  // k_phys base for this thread
    const size_t vbase = (((size_t)(b * 16 + h) * 32 + sb) * 64 + d) * 64;
#pragma unroll
    for (int g = 0; g < 4; ++g) {  // g = oct of k_phys
      ushort4 u;
      u.x = f2b(Vs[sc0 + g * 4 + 0][d]);
      u.y = f2b(Vs[sc0 + g * 4 + 1][d]);
      u.z = f2b(Vs[sc0 + g * 4 + 2][d]);
      u.w = f2b(Vs[sc0 + g * 4 + 3][d]);
      *(ushort4*)(Vtg + vbase + m * 32 + g * 8 + tp * 4) = u;
    }
  }
}

// ---- attn tile step: GUARANTEED-INLINE free function (state by reference) --
__device__ __forceinline__ void attn_tile_step(
    const unsigned short* KV, int buf, int fr, int oct, int g,
    bf16x8 q0s0, bf16x8 q1s0, bf16x8 q0s1, bf16x8 q1s1, bool domask,
    float (&m_prev)[2], f32x4 (&acc)[2][4], f32x4 (&accl)[2], bf16x8 onesf) {
  const unsigned short* Kbuf = &KV[buf * 4608];
  const unsigned short* Vbuf = &KV[(4 + buf) * 4608];
  // K fragments: read ONCE, used by both strips
  bf16x8 kf0[4], kf1[4];
#pragma unroll
  for (int t = 0; t < 4; ++t) {
    kf0[t] = __builtin_bit_cast(bf16x8, *(const uint4*)&Kbuf[(t * 16 + fr) * 72 + oct * 8]);
    kf1[t] = __builtin_bit_cast(bf16x8, *(const uint4*)&Kbuf[(t * 16 + fr) * 72 + 32 + oct * 8]);
  }
  f32x4 s4[2][4];
  __builtin_amdgcn_s_setprio(1);
#pragma unroll
  for (int s = 0; s < 2; ++s) {
    const bf16x8 Q0 = (s == 0) ? q0s0 : q0s1;
    const bf16x8 Q1 = (s == 0) ? q1s0 : q1s1;
#pragma unroll
    for (int t = 0; t < 4; ++t) {
      f32x4 ss = {};
      ss = __builtin_amdgcn_mfma_f32_16x16x32_bf16(kf0[t], Q0, ss, 0, 0, 0);
      ss = __builtin_amdgcn_mfma_f32_16x16x32_bf16(kf1[t], Q1, ss, 0, 0, 0);
      s4[s][t] = ss;
    }
  }
  __builtin_amdgcn_s_setprio(0);
  if (domask) {
#pragma unroll
    for (int s = 0; s < 2; ++s)
#pragma unroll
      for (int t = 0; t < 4; ++t)
#pragma unroll
        for (int r = 0; r < 4; ++r)
          if (t * 16 + oct * 4 + r > g * 32 + s * 16 + fr) s4[s][t][r] = -1e30f;
  }
  // V fragments: read ONCE, used by both strips
  bf16x8 vf0[4], vf1[4];
#pragma unroll
  for (int t = 0; t < 4; ++t) {
    vf0[t] = __builtin_bit_cast(bf16x8, *(const uint4*)&Vbuf[(t * 16 + fr) * 72 + oct * 8]);
    vf1[t] = __builtin_bit_cast(bf16x8, *(const uint4*)&Vbuf[(t * 16 + fr) * 72 + 32 + oct * 8]);
  }

#pragma unroll
  for (int s = 0; s < 2; ++s) {
    float pm = -1e30f;
#pragma unroll
    for (int t = 0; t < 4; ++t)
#pragma unroll
      for (int r = 0; r < 4; ++r) pm = fmaxf(pm, s4[s][t][r]);
    const bool need = __any(pm - m_prev[s] > 11.0f);
    if (need) {
      float pmf = fmaxf(pm, __shfl_xor(pm, 16));
      pmf = fmaxf(pmf, __shfl_xor(pmf, 32));
      float mnew = fmaxf(m_prev[s], pmf);
      float cf = __builtin_amdgcn_exp2f(m_prev[s] - mnew);
      m_prev[s] = mnew;
      float cfr[4];
#pragma unroll
      for (int r = 0; r < 4; ++r) cfr[r] = __shfl(cf, oct * 4 + r);
#pragma unroll
      for (int t2 = 0; t2 < 4; ++t2)
#pragma unroll
        for (int r = 0; r < 4; ++r) acc[s][t2][r] *= cfr[r];
#pragma unroll
      for (int r = 0; r < 4; ++r) accl[s][r] *= cfr[r];
    }
    const float mc = m_prev[s];
#pragma unroll
    for (int t = 0; t < 4; ++t)
#pragma unroll
      for (int r = 0; r < 4; ++r)
        s4[s][t][r] = __builtin_amdgcn_exp2f(s4[s][t][r] - mc);

    uint4 pw0, pw1;
    pw0.x = cvtpk(s4[s][0][0], s4[s][0][1]); pw0.y = cvtpk(s4[s][0][2], s4[s][0][3]);
    pw0.z = cvtpk(s4[s][1][0], s4[s][1][1]); pw0.w = cvtpk(s4[s][1][2], s4[s][1][3]);
    pw1.x = cvtpk(s4[s][2][0], s4[s][2][1]); pw1.y = cvtpk(s4[s][2][2], s4[s][2][3]);
    pw1.z = cvtpk(s4[s][3][0], s4[s][3][1]); pw1.w = cvtpk(s4[s][3][2], s4[s][3][3]);
    const bf16x8 pa0 = __builtin_bit_cast(bf16x8, pw0);
    const bf16x8 pa1 = __builtin_bit_cast(bf16x8, pw1);

    __builtin_amdgcn_s_setprio(1);
#pragma unroll
    for (int t2 = 0; t2 < 4; ++t2) {
      f32x4 a = acc[s][t2];
      a = __builtin_amdgcn_mfma_f32_16x16x32_bf16(pa0, vf0[t2], a, 0, 0, 0);
      a = __builtin_amdgcn_mfma_f32_16x16x32_bf16(pa1, vf1[t2], a, 0, 0, 0);
      acc[s][t2] = a;
    }
    {
      f32x4 a = accl[s];
      a = __builtin_amdgcn_mfma_f32_16x16x32_bf16(pa0, onesf, a, 0, 0, 0);
      a = __builtin_amdgcn_mfma_f32_16x16x32_bf16(pa1, onesf, a, 0, 0, 0);
      accl[s] = a;
    }
    __builtin_amdgcn_s_setprio(0);
  }
}

// ---- attn output write: GUARANTEED-INLINE free function --------------------
__device__ __forceinline__ void attn_write_out(
    unsigned short* __restrict__ attnb, int b, int h, int qtile, int g,
    int oct, int fr, const f32x4 (&acc)[2][4], const f32x4 (&accl)[2]) {
#pragma unroll
  for (int s = 0; s < 2; ++s)
#pragma unroll
    for (int r = 0; r < 4; ++r) {
      float linv = 1.f / accl[s][r];
      size_t orow = (size_t)(b * 2048 + qtile * 64 + g * 32 + s * 16 + oct * 4 + r);
#pragma unroll
      for (int t2 = 0; t2 < 4; ++t2)
        attnb[orow * 1024 + h * 64 + t2 * 16 + fr] = f2b(acc[s][t2][r] * linv);
    }
}

// --------------------------- MFMA flash attention ---------------------------
// Block = (p, h, b): qt0 = p, qt1 = 31-p. 256 threads = 4 waves; group A =
// waves {0,1} (qt0), group B = waves {2,3} (qt1); wave's g = w&1 selects its
// 32-row half. Each wave reads K/V fragments ONCE per 36 MFMAs. ALL helpers
// are forceinline free functions (no lambdas -> no outlining -> no scratch).
// Phase 1 (kb=0..qt0): shared staging, dbuf {0,1}. A flushes qt0, resets.
// Phase 2: A:[qt0+1..16] bufs {0,1}, B:[17..qt1] bufs {2,3}; per-group
// staging covers all 64 rows. Merge via LDS overlay. LDS stride 72.
// 8 bufs x [64][72] = 73728 B -> 2 blocks/CU.
__global__ __launch_bounds__(256, 2) void attn_mfma(const unsigned short* __restrict__ Qb,
                                                    const unsigned short* __restrict__ Kb,
                                                    const unsigned short* __restrict__ Vtg,
                                                    unsigned short* __restrict__ attnb) {
  extern __shared__ unsigned short KV[];  // [8][64][72]
  const int h = blockIdx.y, b = blockIdx.z;
  const int qt0 = blockIdx.x;   // 0..15
  const int qt1 = 31 - qt0;     // 16..31
  const int tid = threadIdx.x, lane = tid & 63, w = tid >> 6;  // 4 waves
  const int fr = lane & 15, oct = lane >> 4;
  const int grp = w >> 1, g = w & 1;
  const int nhA = 16 - qt0, nhB = 15 - qt0;

  const size_t bh = (size_t)(b * 16 + h);
  const unsigned short* Kbase = Kb + bh * 131072;
  const unsigned short* Vbase = Vtg + bh * 131072;

  // Q fragments (scalars; constant-indexed, never address-taken)
  const int qtP1 = grp ? qt1 : qt0;
  const unsigned short* QpA0 = Qb + (bh * 2048 + qtP1 * 64 + g * 32 + fr) * 64;
  const unsigned short* QpA1 = QpA0 + 16 * 64;
  const bf16x8 qa0s0 = __builtin_bit_cast(bf16x8, *(const uint4*)(QpA0 + oct * 8));
  const bf16x8 qa1s0 = __builtin_bit_cast(bf16x8, *(const uint4*)(QpA0 + 32 + oct * 8));
  const bf16x8 qa0s1 = __builtin_bit_cast(bf16x8, *(const uint4*)(QpA1 + oct * 8));
  const bf16x8 qa1s1 = __builtin_bit_cast(bf16x8, *(const uint4*)(QpA1 + 32 + oct * 8));
  const unsigned short* QpB0 = Qb + (bh * 2048 + qt1 * 64 + g * 32 + fr) * 64;
  const unsigned short* QpB1 = QpB0 + 16 * 64;
  const bf16x8 qb0s0 = __builtin_bit_cast(bf16x8, *(const uint4*)(QpB0 + oct * 8));
  const bf16x8 qb1s0 = __builtin_bit_cast(bf16x8, *(const uint4*)(QpB0 + 32 + oct * 8));
  const bf16x8 qb0s1 = __builtin_bit_cast(bf16x8, *(const uint4*)(QpB1 + oct * 8));
  const bf16x8 qb1s1 = __builtin_bit_cast(bf16x8, *(const uint4*)(QpB1 + 32 + oct * 8));

  float m_prev[2] = {-1e30f, -1e30f};
  f32x4 acc[2][4] = {};   // acc[s][t2][r] = O[q=g*32+s*16+oct*4+r][d=t2*16+fr]
  f32x4 accl[2] = {};

  uint4 onesu;
  onesu.x = 0x3F803F80u; onesu.y = 0x3F803F80u;
  onesu.z = 0x3F803F80u; onesu.w = 0x3F803F80u;
  const bf16x8 onesf = __builtin_bit_cast(bf16x8, onesu);

  // ---- phase-1 staging: 256 threads cover full 64x64 tile (stride 72) ----
  const int sk = tid >> 2, sc = (tid & 3) * 16;
  const unsigned short* kp1 = Kbase + sk * 64 + sc;
  const unsigned short* vp1 = Vbase + sk * 64 + sc;
  {
    uint4 k0 = *(const uint4*)kp1, k1 = *(const uint4*)(kp1 + 8);
    uint4 v0 = *(const uint4*)vp1, v1 = *(const uint4*)(vp1 + 8);
    *(uint4*)&KV[0 * 4608 + sk * 72 + sc] = k0;
    *(uint4*)&KV[0 * 4608 + sk * 72 + sc + 8] = k1;
    *(uint4*)&KV[4 * 4608 + sk * 72 + sc] = v0;
    *(uint4*)&KV[4 * 4608 + sk * 72 + sc + 8] = v1;
  }
  __syncthreads();

  for (int kb = 0; kb <= qt0; ++kb) {
    uint4 k0 = *(const uint4*)(kp1 + (size_t)(kb + 1) * 4096);
    uint4 k1 = *(const uint4*)(kp1 + (size_t)(kb + 1) * 4096 + 8);
    uint4 v0 = *(const uint4*)(vp1 + (size_t)(kb + 1) * 4096);
    uint4 v1 = *(const uint4*)(vp1 + (size_t)(kb + 1) * 4096 + 8);
    uint4 k20, k21, v20, v21;
    const bool extra = (kb == qt0) && (nhB > 0);
    if (extra) {  // pre-stage B's first phase-2 tile (17) into buf 2
      k20 = *(const uint4*)(kp1 + (size_t)17 * 4096);
      k21 = *(const uint4*)(kp1 + (size_t)17 * 4096 + 8);
      v20 = *(const uint4*)(vp1 + (size_t)17 * 4096);
      v21 = *(const uint4*)(vp1 + (size_t)17 * 4096 + 8);
    }
    attn_tile_step(KV, kb & 1, fr, oct, g, qa0s0, qa1s0, qa0s1, qa1s1,
                   kb == qtP1, m_prev, acc, accl, onesf);
    const int nb = (kb + 1) & 1;
    *(uint4*)&KV[nb * 4608 + sk * 72 + sc] = k0;
    *(uint4*)&KV[nb * 4608 + sk * 72 + sc + 8] = k1;
    *(uint4*)&KV[(4 + nb) * 4608 + sk * 72 + sc] = v0;
    *(uint4*)&KV[(4 + nb) * 4608 + sk * 72 + sc + 8] = v1;
    if (extra) {
      *(uint4*)&KV[2 * 4608 + sk * 72 + sc] = k20;
      *(uint4*)&KV[2 * 4608 + sk * 72 + sc + 8] = k21;
      *(uint4*)&KV[6 * 4608 + sk * 72 + sc] = v20;
      *(uint4*)&KV[6 * 4608 + sk * 72 + sc + 8] = v21;
    }
    __syncthreads();
  }

  // group A: flush qt0 output, reset state for phase-2 partial
  if (grp == 0) {
    attn_write_out(attnb, b, h, qt0, g, oct, fr, acc, accl);
    f32x4 zz = {};
#pragma unroll
    for (int s = 0; s < 2; ++s) {
      m_prev[s] = -1e30f;
      accl[s] = zz;
#pragma unroll
      for (int t2 = 0; t2 < 4; ++t2) acc[s][t2] = zz;
    }
  }

  // ---- phase 2: A takes kb=qt0+1..16, B takes kb=17..qt1 ----
  // per-group staging covers ALL 64 rows: 128 threads, 2 thr/row x 32 cols
  const int t2i = tid & 127;
  const int sk2 = t2i >> 1, sc2 = (t2i & 1) * 32;
  const unsigned short* kp2 = Kbase + sk2 * 64 + sc2;
  const unsigned short* vp2 = Vbase + sk2 * 64 + sc2;
  const int cnt = grp ? nhB : nhA;
  for (int i = 0; i < nhA; ++i) {
    const int kbm = grp ? (17 + i) : (qt0 + 1 + i);
    const int buf = grp ? (2 + (i & 1)) : (kbm & 1);
    uint4 kq[4], vq[4];
    const bool pf = (i + 1 < cnt);
    if (pf) {
      const unsigned short* ks = kp2 + (size_t)(kbm + 1) * 4096;
      const unsigned short* vs = vp2 + (size_t)(kbm + 1) * 4096;
#pragma unroll
      for (int q = 0; q < 4; ++q) {
        kq[q] = *(const uint4*)(ks + q * 8);
        vq[q] = *(const uint4*)(vs + q * 8);
      }
    }
    if (i < cnt)
      attn_tile_step(KV, buf, fr, oct, g, qb0s0, qb1s0, qb0s1, qb1s1,
                     kbm == qt1, m_prev, acc, accl, onesf);
    if (pf) {
      const int nb = grp ? (2 + ((i + 1) & 1)) : ((kbm + 1) & 1);
#pragma unroll
      for (int q = 0; q < 4; ++q) {
        *(uint4*)&KV[nb * 4608 + sk2 * 72 + sc2 + q * 8] = kq[q];
        *(uint4*)&KV[(4 + nb) * 4608 + sk2 * 72 + sc2 + q * 8] = vq[q];
      }
    }
    __syncthreads();
  }

  // ---- merge partials (B -> LDS overlay, A combines and writes qt1) ----
  float* MF = (float*)KV;  // overlays dead K/V buffers
  // acc: MF[(row)*68 + col] rows 0-63; l: MF[4352+row]; m: MF[4416+qcol]
  if (grp == 1) {
#pragma unroll
    for (int s = 0; s < 2; ++s) {
#pragma unroll
      for (int t2 = 0; t2 < 4; ++t2)
#pragma unroll
        for (int r = 0; r < 4; ++r)
          MF[(g * 32 + s * 16 + oct * 4 + r) * 68 + t2 * 16 + fr] = acc[s][t2][r];
      if (fr == 0) {
#pragma unroll
        for (int r = 0; r < 4; ++r)
          MF[4352 + g * 32 + s * 16 + oct * 4 + r] = accl[s][r];
      }
      if (oct == 0) MF[4416 + g * 32 + s * 16 + fr] = m_prev[s];
    }
  }
  __syncthreads();
  if (grp == 0) {
#pragma unroll
    for (int s = 0; s < 2; ++s) {
      float mB = MF[4416 + g * 32 + s * 16 + fr];
      float mS = fmaxf(m_prev[s], mB);
      float fA = __builtin_amdgcn_exp2f(m_prev[s] - mS);
      float fB = __builtin_amdgcn_exp2f(mB - mS);
      float fAr[4], fBr[4];
#pragma unroll
      for (int r = 0; r < 4; ++r) {
        fAr[r] = __shfl(fA, oct * 4 + r);
        fBr[r] = __shfl(fB, oct * 4 + r);
      }
#pragma unroll
      for (int r = 0; r < 4; ++r)
        accl[s][r] = accl[s][r] * fAr[r] +
                     MF[4352 + g * 32 + s * 16 + oct * 4 + r] * fBr[r];
#pragma unroll
      for (int t2 = 0; t2 < 4; ++t2)
#pragma unroll
        for (int r = 0; r < 4; ++r)
          acc[s][t2][r] =
              acc[s][t2][r] * fAr[r] +
              MF[(g * 32 + s * 16 + oct * 4 + r) * 68 + t2 * 16 + fr] * fBr[r];
    }
    attn_write_out(attnb, b, h, qt1, g, oct, fr, acc, accl);
  }
}

// ---------------------------------------------------------------------------
extern "C" void kernel_launch(void* const* d_in, const int* in_sizes, int n_in,
                              void* d_out, int out_size, void* d_ws, size_t ws_size,
                              hipStream_t stream) {
  const float* x     = (const float*)d_in[0];  // [2,2048,1024]
  const float* w_qkv = (const float*)d_in[1];  // [1024,3072]
  const float* w_out = (const float*)d_in[2];  // [1024,1024]
  const float* freqs = (const float*)d_in[3];  // [2048,64]
  float* out = (float*)d_out;

  char* ws = (char*)d_ws;
  unsigned short* qkvb = (unsigned short*)(ws);             // 25165824
  unsigned short* Qb   = (unsigned short*)(ws + 25165824);  // 8388608
  unsigned short* Kb   = (unsigned short*)(ws + 33554432);  // 8388608
  unsigned short* Vtg  = (unsigned short*)(ws + 41943040);  // 8388608
  unsigned short* attnb= (unsigned short*)(ws + 50331648);  // 8388608
  unsigned short* wqT  = (unsigned short*)(ws + 58720256);  // 6291456
  unsigned short* woT  = (unsigned short*)(ws + 65011712);  // 2097152
  unsigned short* xb   = (unsigned short*)(ws + 67108864);  // 8388608
  float* cosT          = (float*)(ws + 75497472);           // 524288
  float* sinT          = (float*)(ws + 76021760);           // 524288
  // total ws use: 76546048 bytes (~73 MiB)

  (void)hipFuncSetAttribute((const void*)gemm_wide,
                            hipFuncAttributeMaxDynamicSharedMemorySize, 81920);
  (void)hipFuncSetAttribute((const void*)gemm2_ring,
                            hipFuncAttributeMaxDynamicSharedMemorySize, 49152);
  (void)hipFuncSetAttribute((const void*)attn_mfma,
                            hipFuncAttributeMaxDynamicSharedMemorySize, 73728);

  convert_bf16<<<4096, 256, 0, stream>>>(x, xb, 4096 * 1024);
  trig_kernel<<<512, 256, 0, stream>>>(freqs, cosT, sinT, 2048 * 64);
  transpose_f32_bf16<<<dim3(96, 32), 256, 0, stream>>>(w_qkv, wqT, 1024, 3072);
  transpose_f32_bf16<<<dim3(32, 32), 256, 0, stream>>>(w_out, woT, 1024, 1024);
  gemm_wide<<<dim3(16, 32), 256, 81920, stream>>>(xb, wqT, qkvb, 4096, 3072, 1024);
  prep_kernel<<<dim3(32, 16, 2), 256, 0, stream>>>(qkvb, cosT, sinT, Qb, Kb, Vtg);
  attn_mfma<<<dim3(16, 16, 2), 256, 73728, stream>>>(Qb, Kb, Vtg, attnb);
  gemm2_ring<<<dim3(16, 32), 256, 49152, stream>>>(attnb, woT, out, 4096, 1024, 1024);
}

// Round 20
// 103.917 us; speedup vs baseline: 1.5472x; 1.5472x over previous
//
#include <hip/hip_runtime.h>

// ---------------------------------------------------------------------------
// Fused attention block: qkv GEMM -> RoPE -> causal SDPA (MFMA) -> out GEMM
// B=2 S=2048 D=1024 H=16 DH=64. bf16 MFMA everywhere.
// MFMA fragment mapping (verified r1-r13): A/B-frag outer=lane&15, k=oct*8+e;
// C/D row=oct*4+r, col=lane&15.
// r20: r18 (best, 110us) + the four tiny prologue kernels (convert_bf16,
//      trig, 2x transpose) fused into ONE block-partitioned prologue_kernel
//      (saves 3 launch/tail overheads). Strip attention abandoned: 4
//      structural variants all hit the same register-pressure scratch wall.
// ---------------------------------------------------------------------------

typedef __bf16 bf16x8 __attribute__((ext_vector_type(8)));
typedef float f32x4 __attribute__((ext_vector_type(4)));

__device__ __forceinline__ unsigned short f2b(float f) {
  unsigned int u = __builtin_bit_cast(unsigned int, f);
  unsigned int lsb = (u >> 16) & 1u;
  u += 0x7fffu + lsb;  // round-to-nearest-even
  return (unsigned short)(u >> 16);
}
__device__ __forceinline__ float b2f(unsigned short h) {
  unsigned int u = ((unsigned int)h) << 16;
  return __builtin_bit_cast(float, u);
}
__device__ __forceinline__ unsigned int pk2(float a, float b) {
  return (unsigned int)f2b(a) | ((unsigned int)f2b(b) << 16);
}
__device__ __forceinline__ unsigned int cvtpk(float lo, float hi) {
  unsigned int r;
  asm("v_cvt_pk_bf16_f32 %0, %1, %2" : "=v"(r) : "v"(lo), "v"(hi));
  return r;
}
__device__ __forceinline__ void unp8(uint4 v, float* f) {
  unsigned int u[4] = {v.x, v.y, v.z, v.w};
#pragma unroll
  for (int i = 0; i < 4; ++i) {
    f[2 * i] = b2f((unsigned short)(u[i] & 0xffff));
    f[2 * i + 1] = b2f((unsigned short)(u[i] >> 16));
  }
}
__device__ __forceinline__ void gload16(const void* g, void* l) {
  __builtin_amdgcn_global_load_lds(
      (const __attribute__((address_space(1))) unsigned int*)g,
      (__attribute__((address_space(3))) unsigned int*)l, 16, 0, 0);
}

// ---- fused prologue: convert | trig table | transpose wq | transpose wo ----
// block partition: [0,4096) convert x->xb; [4096,4608) cos/sin table;
// [4608,7680) transpose w_qkv (96x32); [7680,8704) transpose w_out (32x32).
// Branches are block-uniform, so the transpose-branch __syncthreads is safe.
__global__ __launch_bounds__(256) void prologue_kernel(
    const float* __restrict__ x, unsigned short* __restrict__ xb,
    const float* __restrict__ freqs, float* __restrict__ cosT,
    float* __restrict__ sinT, const float* __restrict__ w_qkv,
    unsigned short* __restrict__ wqT, const float* __restrict__ w_out,
    unsigned short* __restrict__ woT) {
  __shared__ float tile[32][33];
  const int blk = blockIdx.x, tid = threadIdx.x;

  if (blk < 4096) {  // convert x (f32) -> xb (bf16), 4 elems/thread
    int i = (blk * 256 + tid) * 4;
    float4 v = *(const float4*)&x[i];
    ushort4 o;
    o.x = f2b(v.x); o.y = f2b(v.y); o.z = f2b(v.z); o.w = f2b(v.w);
    *(ushort4*)&xb[i] = o;
    return;
  }
  if (blk < 4608) {  // cos/sin tables (131072 elems)
    int i = (blk - 4096) * 256 + tid;
    float f = freqs[i];
    cosT[i] = cosf(f);
    sinT[i] = sinf(f);
    return;
  }
  // transpose [K][N] f32 -> [N][K] bf16
  const float* src;
  unsigned short* dst;
  int K, N, bx, by;
  if (blk < 7680) {
    src = w_qkv; dst = wqT; K = 1024; N = 3072;
    const int t = blk - 4608;
    bx = t % 96; by = t / 96;
  } else {
    src = w_out; dst = woT; K = 1024; N = 1024;
    const int t = blk - 7680;
    bx = t % 32; by = t / 32;
  }
  const int n0 = bx * 32, k0 = by * 32;
  const int c = tid & 31, r4 = tid >> 5;
#pragma unroll
  for (int p = 0; p < 4; ++p) {
    int r = r4 + p * 8;
    tile[r][c] = src[(size_t)(k0 + r) * N + n0 + c];
  }
  __syncthreads();
#pragma unroll
  for (int p = 0; p < 4; ++p) {
    int r = r4 + p * 8;
    dst[(size_t)(n0 + r) * K + k0 + c] = f2b(tile[c][r]);
  }
}

// ------------- wide-grid ring-buffered bf16 GEMM (for qkv GEMM) ------------
// 128x192 tile, BK=32, 256 thr = 4 waves (2M x 2N), per-wave 64x96 (acc 4x6).
// Ring of 4 LDS slots (20 KB) = 80 KB -> 2 blocks/CU; grid (16,32) = 512
// blocks. Counted vmcnt(10); epilogue ladder 10/5/0.
__global__ __launch_bounds__(256, 2) void gemm_wide(const unsigned short* __restrict__ A,
                                                    const unsigned short* __restrict__ BT,
                                                    unsigned short* __restrict__ C,
                                                    int M, int N, int K) {
  extern __shared__ unsigned short L[];  // 4 slots x 10240 ushort = 80 KB
  const int tid = threadIdx.x, lane = tid & 63, w = tid >> 6;
  const int wr = w >> 1, wc = w & 1;
  const int fr = lane & 15, oct = lane >> 4;

  const int m0 = blockIdx.y * 128, n0 = blockIdx.x * 192;

  const int sr = tid >> 2;                                 // 0..63
  const int scol = ((tid & 3) ^ ((tid >> 3) & 3)) * 8;     // swizzled src col
  const size_t aR0 = (size_t)(m0 + sr) * K + scol;
  const size_t aR1 = (size_t)(m0 + 64 + sr) * K + scol;
  const size_t bR0 = (size_t)(n0 + sr) * K + scol;
  const size_t bR1 = (size_t)(n0 + 64 + sr) * K + scol;
  const size_t bR2 = (size_t)(n0 + 128 + sr) * K + scol;

  f32x4 acc[4][6] = {};
  const int T = K >> 5;

  for (int pt = 0; pt < 3; ++pt) {  // prologue: stage tiles 0,1,2
    unsigned short* Ln = &L[pt * 10240];
    const size_t gk = (size_t)pt * 32;
    gload16(&A[aR0 + gk], &Ln[tid * 8]);
    gload16(&A[aR1 + gk], &Ln[2048 + tid * 8]);
    gload16(&BT[bR0 + gk], &Ln[4096 + tid * 8]);
    gload16(&BT[bR1 + gk], &Ln[6144 + tid * 8]);
    gload16(&BT[bR2 + gk], &Ln[8192 + tid * 8]);
  }

  for (int t = 0; t < T; ++t) {
    if (t + 3 <= T) {
      asm volatile("s_waitcnt vmcnt(10)" ::: "memory");
    } else if (t + 2 == T) {
      asm volatile("s_waitcnt vmcnt(5)" ::: "memory");
    } else {
      asm volatile("s_waitcnt vmcnt(0)" ::: "memory");
    }
    __builtin_amdgcn_sched_barrier(0);
    __builtin_amdgcn_s_barrier();
    __builtin_amdgcn_sched_barrier(0);

    const unsigned short* Lb = &L[(t & 3) * 10240];
    unsigned short* Ln = &L[((t + 3) & 3) * 10240];
    const size_t gk = (size_t)(t + 3) * 32;
    const bool doStage = (t + 3 < T);

    bf16x8 af[4], bf[6];
#pragma unroll
    for (int i = 0; i < 4; ++i) {
      const int ra = wr * 64 + i * 16 + fr;
      af[i] = __builtin_bit_cast(
          bf16x8, *(const uint4*)&Lb[ra * 32 + ((oct ^ ((ra >> 1) & 3)) * 8)]);
    }
#pragma unroll
    for (int j = 0; j < 3; ++j) {
      const int rb = wc * 96 + j * 16 + fr;
      bf[j] = __builtin_bit_cast(
          bf16x8,
          *(const uint4*)&Lb[4096 + rb * 32 + ((oct ^ ((rb >> 1) & 3)) * 8)]);
    }
    if (doStage) {
      gload16(&A[aR0 + gk], &Ln[tid * 8]);
      gload16(&A[aR1 + gk], &Ln[2048 + tid * 8]);
      gload16(&BT[bR0 + gk], &Ln[4096 + tid * 8]);
    }
    __builtin_amdgcn_s_setprio(1);
#pragma unroll
    for (int i = 0; i < 4; ++i)
#pragma unroll
      for (int j = 0; j < 3; ++j)
        acc[i][j] = __builtin_amdgcn_mfma_f32_16x16x32_bf16(af[i], bf[j], acc[i][j], 0, 0, 0);
    __builtin_amdgcn_s_setprio(0);

#pragma unroll
    for (int j = 3; j < 6; ++j) {
      const int rb = wc * 96 + j * 16 + fr;
      bf[j] = __builtin_bit_cast(
          bf16x8,
          *(const uint4*)&Lb[4096 + rb * 32 + ((oct ^ ((rb >> 1) & 3)) * 8)]);
    }
    if (doStage) {
      gload16(&BT[bR1 + gk], &Ln[6144 + tid * 8]);
      gload16(&BT[bR2 + gk], &Ln[8192 + tid * 8]);
    }
    __builtin_amdgcn_s_setprio(1);
#pragma unroll
    for (int i = 0; i < 4; ++i)
#pragma unroll
      for (int j = 3; j < 6; ++j)
        acc[i][j] = __builtin_amdgcn_mfma_f32_16x16x32_bf16(af[i], bf[j], acc[i][j], 0, 0, 0);
    __builtin_amdgcn_s_setprio(0);
  }

#pragma unroll
  for (int i = 0; i < 4; ++i)
#pragma unroll
    for (int j = 0; j < 6; ++j)
#pragma unroll
      for (int r = 0; r < 4; ++r)
        C[(size_t)(m0 + wr * 64 + i * 16 + oct * 4 + r) * N + n0 + wc * 96 +
          j * 16 + fr] = f2b(acc[i][j][r]);
}

// ---------------- ring-buffered bf16 GEMM for out GEMM (f32 C) -------------
// 128x64 tile, BK=32, 256 thr = 4 waves (2M x 2N), per-wave 64x32 (acc 4x2).
// Ring of 4 LDS slots (12 KB) = 48 KB -> 2 blocks/CU; grid (16,32) = 512
// blocks. 3 stage-issues/tile; counted vmcnt(6); epilogue ladder 6/3/0.
__global__ __launch_bounds__(256, 2) void gemm2_ring(const unsigned short* __restrict__ A,
                                                     const unsigned short* __restrict__ BT,
                                                     float* __restrict__ C,
                                                     int M, int N, int K) {
  extern __shared__ unsigned short L[];  // 4 slots x 6144 ushort = 48 KB
  const int tid = threadIdx.x, lane = tid & 63, w = tid >> 6;
  const int wr = w >> 1, wc = w & 1;
  const int fr = lane & 15, oct = lane >> 4;
  const int m0 = blockIdx.y * 128, n0 = blockIdx.x * 64;

  const int sr = tid >> 2;
  const int scol = ((tid & 3) ^ ((tid >> 3) & 3)) * 8;  // swizzled src col
  const size_t aR0 = (size_t)(m0 + sr) * K + scol;
  const size_t aR1 = (size_t)(m0 + 64 + sr) * K + scol;
  const size_t bR0 = (size_t)(n0 + sr) * K + scol;

  f32x4 acc[4][2] = {};
  const int T = K >> 5;

  for (int pt = 0; pt < 3; ++pt) {  // prologue: stage tiles 0,1,2
    unsigned short* Ln = &L[pt * 6144];
    const size_t gk = (size_t)pt * 32;
    gload16(&A[aR0 + gk], &Ln[tid * 8]);
    gload16(&A[aR1 + gk], &Ln[2048 + tid * 8]);
    gload16(&BT[bR0 + gk], &Ln[4096 + tid * 8]);
  }

  for (int t = 0; t < T; ++t) {
    if (t + 3 <= T) {
      asm volatile("s_waitcnt vmcnt(6)" ::: "memory");
    } else if (t + 2 == T) {
      asm volatile("s_waitcnt vmcnt(3)" ::: "memory");
    } else {
      asm volatile("s_waitcnt vmcnt(0)" ::: "memory");
    }
    __builtin_amdgcn_sched_barrier(0);
    __builtin_amdgcn_s_barrier();
    __builtin_amdgcn_sched_barrier(0);

    const unsigned short* Lb = &L[(t & 3) * 6144];
    unsigned short* Ln = &L[((t + 3) & 3) * 6144];
    const size_t gk = (size_t)(t + 3) * 32;
    const bool doStage = (t + 3 < T);

    bf16x8 af[4], bq[2];
#pragma unroll
    for (int i = 0; i < 4; ++i) {
      const int ra = wr * 64 + i * 16 + fr;
      af[i] = __builtin_bit_cast(
          bf16x8, *(const uint4*)&Lb[ra * 32 + ((oct ^ ((ra >> 1) & 3)) * 8)]);
    }
#pragma unroll
    for (int j = 0; j < 2; ++j) {
      const int rb = wc * 32 + j * 16 + fr;
      bq[j] = __builtin_bit_cast(
          bf16x8,
          *(const uint4*)&Lb[4096 + rb * 32 + ((oct ^ ((rb >> 1) & 3)) * 8)]);
    }
    if (doStage) {
      gload16(&A[aR0 + gk], &Ln[tid * 8]);
      gload16(&A[aR1 + gk], &Ln[2048 + tid * 8]);
      gload16(&BT[bR0 + gk], &Ln[4096 + tid * 8]);
    }
    __builtin_amdgcn_s_setprio(1);
#pragma unroll
    for (int i = 0; i < 4; ++i)
#pragma unroll
      for (int j = 0; j < 2; ++j)
        acc[i][j] = __builtin_amdgcn_mfma_f32_16x16x32_bf16(af[i], bq[j], acc[i][j], 0, 0, 0);
    __builtin_amdgcn_s_setprio(0);
  }

#pragma unroll
  for (int i = 0; i < 4; ++i)
#pragma unroll
    for (int j = 0; j < 2; ++j)
#pragma unroll
      for (int r = 0; r < 4; ++r)
        C[(size_t)(m0 + wr * 64 + i * 16 + oct * 4 + r) * N + n0 + wc * 32 +
          j * 16 + fr] = acc[i][j][r];
}

// ----------------- prep: RoPE + layout (Q,K rows; V tile-blocked+permuted) --
__global__ __launch_bounds__(256) void prep_kernel(const unsigned short* __restrict__ qkvb,
                                                   const float* __restrict__ cosT,
                                                   const float* __restrict__ sinT,
                                                   unsigned short* __restrict__ Qb,
                                                   unsigned short* __restrict__ Kb,
                                                   unsigned short* __restrict__ Vtg) {
  const int sb = blockIdx.x, h = blockIdx.y, b = blockIdx.z;
  const int tid = threadIdx.x;
  __shared__ float Vs[64][65];
  const int sl = tid >> 2, c8 = (tid & 3) * 8;
  const int s = sb * 64 + sl;
  const size_t tok = (size_t)(b * 2048 + s);
  const unsigned short* row = qkvb + tok * 3072 + h * 64;
  const float QSCALE = 0.125f * 1.44269504f;

  float cl[8], snl[8], ch[8], snh[8];
  {
    const float* cb = cosT + s * 64;
    const float* sbp = sinT + s * 64;
    *(float4*)&cl[0] = *(const float4*)&cb[c8];
    *(float4*)&cl[4] = *(const float4*)&cb[c8 + 4];
    *(float4*)&ch[0] = *(const float4*)&cb[32 + c8];
    *(float4*)&ch[4] = *(const float4*)&cb[32 + c8 + 4];
    *(float4*)&snl[0] = *(const float4*)&sbp[c8];
    *(float4*)&snl[4] = *(const float4*)&sbp[c8 + 4];
    *(float4*)&snh[0] = *(const float4*)&sbp[32 + c8];
    *(float4*)&snh[4] = *(const float4*)&sbp[32 + c8 + 4];
  }
  const size_t obase = ((size_t)(b * 16 + h) * 2048 + s) * 64;

  // Q (scaled)
  {
    float lo[8], hi[8];
    unp8(*(const uint4*)(row + c8), lo);
    unp8(*(const uint4*)(row + 32 + c8), hi);
    float olo[8], ohi[8];
#pragma unroll
    for (int e = 0; e < 8; ++e) {
      olo[e] = (lo[e] * cl[e] - hi[e] * snl[e]) * QSCALE;
      ohi[e] = (hi[e] * ch[e] + lo[e] * snh[e]) * QSCALE;
    }
    uint4 w0, w1;
    w0.x = pk2(olo[0], olo[1]); w0.y = pk2(olo[2], olo[3]);
    w0.z = pk2(olo[4], olo[5]); w0.w = pk2(olo[6], olo[7]);
    w1.x = pk2(ohi[0], ohi[1]); w1.y = pk2(ohi[2], ohi[3]);
    w1.z = pk2(ohi[4], ohi[5]); w1.w = pk2(ohi[6], ohi[7]);
    *(uint4*)(Qb + obase + c8) = w0;
    *(uint4*)(Qb + obase + 32 + c8) = w1;
  }
  // K
  {
    float lo[8], hi[8];
    unp8(*(const uint4*)(row + 1024 + c8), lo);
    unp8(*(const uint4*)(row + 1024 + 32 + c8), hi);
    float olo[8], ohi[8];
#pragma unroll
    for (int e = 0; e < 8; ++e) {
      olo[e] = lo[e] * cl[e] - hi[e] * snl[e];
      ohi[e] = hi[e] * ch[e] + lo[e] * snh[e];
    }
    uint4 w0, w1;
    w0.x = pk2(olo[0], olo[1]); w0.y = pk2(olo[2], olo[3]);
    w0.z = pk2(olo[4], olo[5]); w0.w = pk2(olo[6], olo[7]);
    w1.x = pk2(ohi[0], ohi[1]); w1.y = pk2(ohi[2], ohi[3]);
    w1.z = pk2(ohi[4], ohi[5]); w1.w = pk2(ohi[6], ohi[7]);
    *(uint4*)(Kb + obase + c8) = w0;
    *(uint4*)(Kb + obase + 32 + c8) = w1;
  }
  // V -> LDS f32, then tile-blocked + k-permuted bf16 out
  {
    float lo[8], hi[8];
    unp8(*(const uint4*)(row + 2048 + c8), lo);
    unp8(*(const uint4*)(row + 2048 + 32 + c8), hi);
#pragma unroll
    for (int e = 0; e < 8; ++e) {
      Vs[sl][c8 + e] = lo[e];
      Vs[sl][32 + c8 + e] = hi[e];
    }
  }
  __syncthreads();
  {
    const int d = tid >> 2, q2 = tid & 3;
    const int m = q2 >> 1, tp = q2 & 1;
    const int sc0 = q2 * 16;  // k_phys base for this thread
    const size_t vbase = (((size_t)(b * 16 + h) * 32 + sb) * 64 + d) * 64;
#pragma unroll
    for (int g = 0; g < 4; ++g) {  // g = oct of k_phys
      ushort4 u;
      u.x = f2b(Vs[sc0 + g * 4 + 0][d]);
      u.y = f2b(Vs[sc0 + g * 4 + 1][d]);
      u.z = f2b(Vs[sc0 + g * 4 + 2][d]);
      u.w = f2b(Vs[sc0 + g * 4 + 3][d]);
      *(ushort4*)(Vtg + vbase + m * 32 + g * 8 + tp * 4) = u;
    }
  }
}

// --------------------------- MFMA flash attention ---------------------------
// (byte-exact r13 kernel: proven 41us, WRITE 8MB, VGPR 48)
// Block = (p, h, b): qt0 = p, qt1 = 31-p. 512 threads = 8 waves; group A =
// waves 0-3, group B = waves 4-7. Phase 1 (kb=0..qt0): A computes qt0, B
// computes qt1, shared staging, dbuf {0,1}. Then A flushes qt0 and resets.
// Phase 2: qt1's remaining tiles split A:[qt0+1..16] (bufs {0,1}),
// B:[17..qt1] (bufs {2,3}); partial (m,l,O) merged via LDS overlay. Every
// block = exactly 17 iterations. Dynamic LDS: 73728 B -> 2 blocks/CU.
__global__ __launch_bounds__(512, 4) void attn_mfma(const unsigned short* __restrict__ Qb,
                                                    const unsigned short* __restrict__ Kb,
                                                    const unsigned short* __restrict__ Vtg,
                                                    unsigned short* __restrict__ attnb) {
  extern __shared__ unsigned short KV[];  // [8][64][72]
  const int h = blockIdx.y, b = blockIdx.z;
  const int qt0 = blockIdx.x;   // 0..15
  const int qt1 = 31 - qt0;     // 16..31
  const int tid = threadIdx.x, lane = tid & 63, w = tid >> 6;
  const int fr = lane & 15, oct = lane >> 4;
  const int grp = w >> 2, wq = w & 3;
  const int nhA = 16 - qt0, nhB = 15 - qt0;

  const size_t bh = (size_t)(b * 16 + h);
  const unsigned short* Kbase = Kb + bh * 131072;
  const unsigned short* Vbase = Vtg + bh * 131072;

  const int qtP1 = grp ? qt1 : qt0;
  const unsigned short* Qp1 = Qb + (bh * 2048 + qtP1 * 64 + wq * 16 + fr) * 64;
  const bf16x8 qa0 = __builtin_bit_cast(bf16x8, *(const uint4*)(Qp1 + oct * 8));
  const bf16x8 qa1 = __builtin_bit_cast(bf16x8, *(const uint4*)(Qp1 + 32 + oct * 8));
  const unsigned short* Qp2 = Qb + (bh * 2048 + qt1 * 64 + wq * 16 + fr) * 64;
  const bf16x8 qb0 = __builtin_bit_cast(bf16x8, *(const uint4*)(Qp2 + oct * 8));
  const bf16x8 qb1 = __builtin_bit_cast(bf16x8, *(const uint4*)(Qp2 + 32 + oct * 8));

  float m_prev = -1e30f;
  f32x4 acc[4] = {};
  f32x4 accl = {};

  uint4 onesu;
  onesu.x = 0x3F803F80u; onesu.y = 0x3F803F80u;
  onesu.z = 0x3F803F80u; onesu.w = 0x3F803F80u;
  const bf16x8 onesf = __builtin_bit_cast(bf16x8, onesu);

  auto tile_step = [&](int buf, bf16x8 q0, bf16x8 q1, bool domask) {
    const unsigned short* Kbuf = &KV[buf * 4608];
    const unsigned short* Vbuf = &KV[(4 + buf) * 4608];
    f32x4 s4[4];
    __builtin_amdgcn_s_setprio(1);
#pragma unroll
    for (int t = 0; t < 4; ++t) {
      bf16x8 kf0 = __builtin_bit_cast(bf16x8, *(const uint4*)&Kbuf[(t * 16 + fr) * 72 + oct * 8]);
      bf16x8 kf1 = __builtin_bit_cast(bf16x8, *(const uint4*)&Kbuf[(t * 16 + fr) * 72 + 32 + oct * 8]);
      f32x4 s = {};
      s = __builtin_amdgcn_mfma_f32_16x16x32_bf16(kf0, q0, s, 0, 0, 0);
      s = __builtin_amdgcn_mfma_f32_16x16x32_bf16(kf1, q1, s, 0, 0, 0);
      s4[t] = s;
    }
    __builtin_amdgcn_s_setprio(0);
    if (domask) {
#pragma unroll
      for (int t = 0; t < 4; ++t)
#pragma unroll
        for (int r = 0; r < 4; ++r)
          if (t * 16 + oct * 4 + r > wq * 16 + fr) s4[t][r] = -1e30f;
    }

    float pm = -1e30f;
#pragma unroll
    for (int t = 0; t < 4; ++t)
#pragma unroll
      for (int r = 0; r < 4; ++r) pm = fmaxf(pm, s4[t][r]);
    const bool need = __any(pm - m_prev > 11.0f);
    if (need) {
      float pmf = fmaxf(pm, __shfl_xor(pm, 16));
      pmf = fmaxf(pmf, __shfl_xor(pmf, 32));
      float mnew = fmaxf(m_prev, pmf);
      float cf = __builtin_amdgcn_exp2f(m_prev - mnew);
      m_prev = mnew;
      float cfr[4];
#pragma unroll
      for (int r = 0; r < 4; ++r) cfr[r] = __shfl(cf, oct * 4 + r);
#pragma unroll
      for (int t2 = 0; t2 < 4; ++t2)
#pragma unroll
        for (int r = 0; r < 4; ++r) acc[t2][r] *= cfr[r];
#pragma unroll
      for (int r = 0; r < 4; ++r) accl[r] *= cfr[r];
    }
    const float mc = m_prev;
#pragma unroll
    for (int t = 0; t < 4; ++t)
#pragma unroll
      for (int r = 0; r < 4; ++r)
        s4[t][r] = __builtin_amdgcn_exp2f(s4[t][r] - mc);

    uint4 pw0, pw1;
    pw0.x = cvtpk(s4[0][0], s4[0][1]); pw0.y = cvtpk(s4[0][2], s4[0][3]);
    pw0.z = cvtpk(s4[1][0], s4[1][1]); pw0.w = cvtpk(s4[1][2], s4[1][3]);
    pw1.x = cvtpk(s4[2][0], s4[2][1]); pw1.y = cvtpk(s4[2][2], s4[2][3]);
    pw1.z = cvtpk(s4[3][0], s4[3][1]); pw1.w = cvtpk(s4[3][2], s4[3][3]);
    const bf16x8 pa0 = __builtin_bit_cast(bf16x8, pw0);
    const bf16x8 pa1 = __builtin_bit_cast(bf16x8, pw1);

    __builtin_amdgcn_s_setprio(1);
#pragma unroll
    for (int t2 = 0; t2 < 4; ++t2) {
      bf16x8 vf0 = __builtin_bit_cast(bf16x8, *(const uint4*)&Vbuf[(t2 * 16 + fr) * 72 + oct * 8]);
      bf16x8 vf1 = __builtin_bit_cast(bf16x8, *(const uint4*)&Vbuf[(t2 * 16 + fr) * 72 + 32 + oct * 8]);
      f32x4 a = acc[t2];
      a = __builtin_amdgcn_mfma_f32_16x16x32_bf16(pa0, vf0, a, 0, 0, 0);
      a = __builtin_amdgcn_mfma_f32_16x16x32_bf16(pa1, vf1, a, 0, 0, 0);
      acc[t2] = a;
    }
    {
      f32x4 a = accl;
      a = __builtin_amdgcn_mfma_f32_16x16x32_bf16(pa0, onesf, a, 0, 0, 0);
      a = __builtin_amdgcn_mfma_f32_16x16x32_bf16(pa1, onesf, a, 0, 0, 0);
      accl = a;
    }
    __builtin_amdgcn_s_setprio(0);
  };

  auto write_out = [&](int qtile) {
#pragma unroll
    for (int r = 0; r < 4; ++r) {
      float linv = 1.f / accl[r];
      size_t orow = (size_t)(b * 2048 + qtile * 64 + wq * 16 + oct * 4 + r);
#pragma unroll
      for (int t2 = 0; t2 < 4; ++t2)
        attnb[orow * 1024 + h * 64 + t2 * 16 + fr] = f2b(acc[t2][r] * linv);
    }
  };

  // ---- phase 1 staging (512 threads, 1 uint4 K + 1 uint4 V each) ----
  const int srow = tid >> 3, sc8 = (tid & 7) * 8;
  const unsigned short* kp1 = Kbase + srow * 64 + sc8;
  const unsigned short* vp1 = Vbase + srow * 64 + sc8;
  {
    uint4 kr = *(const uint4*)kp1;
    uint4 vr = *(const uint4*)vp1;
    *(uint4*)&KV[0 * 4608 + srow * 72 + sc8] = kr;
    *(uint4*)&KV[4 * 4608 + srow * 72 + sc8] = vr;
  }
  __syncthreads();

  for (int kb = 0; kb <= qt0; ++kb) {
    uint4 kr = *(const uint4*)(kp1 + (size_t)(kb + 1) * 4096);
    uint4 vr = *(const uint4*)(vp1 + (size_t)(kb + 1) * 4096);
    uint4 kr2, vr2;
    const bool extra = (kb == qt0) && (nhB > 0);
    if (extra) {  // pre-stage B's first phase-2 tile (17) into buf 2
      kr2 = *(const uint4*)(kp1 + (size_t)17 * 4096);
      vr2 = *(const uint4*)(vp1 + (size_t)17 * 4096);
    }
    tile_step(kb & 1, qa0, qa1, kb == qtP1);
    const int nb = (kb + 1) & 1;
    *(uint4*)&KV[nb * 4608 + srow * 72 + sc8] = kr;
    *(uint4*)&KV[(4 + nb) * 4608 + srow * 72 + sc8] = vr;
    if (extra) {
      *(uint4*)&KV[2 * 4608 + srow * 72 + sc8] = kr2;
      *(uint4*)&KV[6 * 4608 + srow * 72 + sc8] = vr2;
    }
    __syncthreads();
  }

  // group A: flush qt0 output, reset state for phase-2 partial
  if (grp == 0) {
    write_out(qt0);
    m_prev = -1e30f;
    f32x4 zz = {};
    accl = zz;
#pragma unroll
    for (int t2 = 0; t2 < 4; ++t2) acc[t2] = zz;
  }

  // ---- phase 2: A takes kb=qt0+1..16, B takes kb=17..qt1 ----
  const int t2id = tid & 255;
  const int sk2 = t2id >> 2, sc2 = (t2id & 3) * 16;
  const int cnt = grp ? nhB : nhA;
  for (int i = 0; i < nhA; ++i) {
    const int kbm = grp ? (17 + i) : (qt0 + 1 + i);
    const int buf = grp ? (2 + (i & 1)) : (kbm & 1);
    uint4 k0, k1, v0, v1;
    const bool pf = (i + 1 < cnt);
    if (pf) {
      const unsigned short* ks = Kbase + (size_t)((kbm + 1) * 64 + sk2) * 64 + sc2;
      const unsigned short* vs = Vbase + (size_t)((kbm + 1) * 64 + sk2) * 64 + sc2;
      k0 = *(const uint4*)ks; k1 = *(const uint4*)(ks + 8);
      v0 = *(const uint4*)vs; v1 = *(const uint4*)(vs + 8);
    }
    if (i < cnt) tile_step(buf, qb0, qb1, kbm == qt1);
    if (pf) {
      const int nb = grp ? (2 + ((i + 1) & 1)) : ((kbm + 1) & 1);
      *(uint4*)&KV[nb * 4608 + sk2 * 72 + sc2] = k0;
      *(uint4*)&KV[nb * 4608 + sk2 * 72 + sc2 + 8] = k1;
      *(uint4*)&KV[(4 + nb) * 4608 + sk2 * 72 + sc2] = v0;
      *(uint4*)&KV[(4 + nb) * 4608 + sk2 * 72 + sc2 + 8] = v1;
    }
    __syncthreads();
  }

  // ---- merge partials (B -> LDS overlay, A combines and writes qt1) ----
  float* MF = (float*)KV;  // overlays dead K/V buffers
  if (grp == 1) {
#pragma unroll
    for (int t2 = 0; t2 < 4; ++t2)
#pragma unroll
      for (int r = 0; r < 4; ++r)
        MF[(wq * 16 + oct * 4 + r) * 68 + t2 * 16 + fr] = acc[t2][r];
    if (fr == 0) {
#pragma unroll
      for (int r = 0; r < 4; ++r) MF[4352 + wq * 16 + oct * 4 + r] = accl[r];
    }
    if (oct == 0) MF[4416 + wq * 16 + fr] = m_prev;
  }
  __syncthreads();
  if (grp == 0) {
    float mB = MF[4416 + wq * 16 + fr];
    float mS = fmaxf(m_prev, mB);
    float fA = __builtin_amdgcn_exp2f(m_prev - mS);
    float fB = __builtin_amdgcn_exp2f(mB - mS);
    float fAr[4], fBr[4];
#pragma unroll
    for (int r = 0; r < 4; ++r) {
      fAr[r] = __shfl(fA, oct * 4 + r);
      fBr[r] = __shfl(fB, oct * 4 + r);
    }
#pragma unroll
    for (int r = 0; r < 4; ++r)
      accl[r] = accl[r] * fAr[r] + MF[4352 + wq * 16 + oct * 4 + r] * fBr[r];
#pragma unroll
    for (int t2 = 0; t2 < 4; ++t2)
#pragma unroll
      for (int r = 0; r < 4; ++r)
        acc[t2][r] = acc[t2][r] * fAr[r] +
                     MF[(wq * 16 + oct * 4 + r) * 68 + t2 * 16 + fr] * fBr[r];
    write_out(qt1);
  }
}

// ---------------------------------------------------------------------------
extern "C" void kernel_launch(void* const* d_in, const int* in_sizes, int n_in,
                              void* d_out, int out_size, void* d_ws, size_t ws_size,
                              hipStream_t stream) {
  const float* x     = (const float*)d_in[0];  // [2,2048,1024]
  const float* w_qkv = (const float*)d_in[1];  // [1024,3072]
  const float* w_out = (const float*)d_in[2];  // [1024,1024]
  const float* freqs = (const float*)d_in[3];  // [2048,64]
  float* out = (float*)d_out;

  char* ws = (char*)d_ws;
  unsigned short* qkvb = (unsigned short*)(ws);             // 25165824
  unsigned short* Qb   = (unsigned short*)(ws + 25165824);  // 8388608
  unsigned short* Kb   = (unsigned short*)(ws + 33554432);  // 8388608
  unsigned short* Vtg  = (unsigned short*)(ws + 41943040);  // 8388608
  unsigned short* attnb= (unsigned short*)(ws + 50331648);  // 8388608
  unsigned short* wqT  = (unsigned short*)(ws + 58720256);  // 6291456
  unsigned short* woT  = (unsigned short*)(ws + 65011712);  // 2097152
  unsigned short* xb   = (unsigned short*)(ws + 67108864);  // 8388608
  float* cosT          = (float*)(ws + 75497472);           // 524288
  float* sinT          = (float*)(ws + 76021760);           // 524288
  // total ws use: 76546048 bytes (~73 MiB)

  (void)hipFuncSetAttribute((const void*)gemm_wide,
                            hipFuncAttributeMaxDynamicSharedMemorySize, 81920);
  (void)hipFuncSetAttribute((const void*)gemm2_ring,
                            hipFuncAttributeMaxDynamicSharedMemorySize, 49152);
  (void)hipFuncSetAttribute((const void*)attn_mfma,
                            hipFuncAttributeMaxDynamicSharedMemorySize, 73728);

  prologue_kernel<<<8704, 256, 0, stream>>>(x, xb, freqs, cosT, sinT, w_qkv,
                                            wqT, w_out, woT);
  gemm_wide<<<dim3(16, 32), 256, 81920, stream>>>(xb, wqT, qkvb, 4096, 3072, 1024);
  prep_kernel<<<dim3(32, 16, 2), 256, 0, stream>>>(qkvb, cosT, sinT, Qb, Kb, Vtg);
  attn_mfma<<<dim3(16, 16, 2), 512, 73728, stream>>>(Qb, Kb, Vtg, attnb);
  gemm2_ring<<<dim3(16, 32), 256, 49152, stream>>>(attnb, woT, out, 4096, 1024, 1024);
}

// Round 21
// 96.336 us; speedup vs baseline: 1.6690x; 1.0787x over previous
//
#include <hip/hip_runtime.h>

// ---------------------------------------------------------------------------
// Fused attention block: qkv GEMM+RoPE+layout -> causal SDPA (MFMA) -> out GEMM
// B=2 S=2048 D=1024 H=16 DH=64. bf16 MFMA everywhere.
// MFMA fragment mapping (verified r1-r13): A/B-frag outer=lane&15, k=oct*8+e;
// C/D row=oct*4+r, col=lane&15.
// r21: prep fused into gemm_wide's epilogue (gemm_fused). B-frag col mapping
//      changed to j*32+wc*16+fr so each RoPE pair (d,d+32) is thread-local
//      and each 64-col block is head-aligned & part-uniform. q/k: RoPE on f32
//      acc -> Qb/Kb. v: LDS 64x66 tile (dead ring slot-0 region) -> prep's
//      transposed+permuted ushort4 write to Vtg. prep_kernel + qkvb gone.
//      prologue/attn/gemm2 byte-identical to r20 (103.9us best).
// ---------------------------------------------------------------------------

typedef __bf16 bf16x8 __attribute__((ext_vector_type(8)));
typedef float f32x4 __attribute__((ext_vector_type(4)));

__device__ __forceinline__ unsigned short f2b(float f) {
  unsigned int u = __builtin_bit_cast(unsigned int, f);
  unsigned int lsb = (u >> 16) & 1u;
  u += 0x7fffu + lsb;  // round-to-nearest-even
  return (unsigned short)(u >> 16);
}
__device__ __forceinline__ float b2f(unsigned short h) {
  unsigned int u = ((unsigned int)h) << 16;
  return __builtin_bit_cast(float, u);
}
__device__ __forceinline__ unsigned int pk2(float a, float b) {
  return (unsigned int)f2b(a) | ((unsigned int)f2b(b) << 16);
}
__device__ __forceinline__ unsigned int cvtpk(float lo, float hi) {
  unsigned int r;
  asm("v_cvt_pk_bf16_f32 %0, %1, %2" : "=v"(r) : "v"(lo), "v"(hi));
  return r;
}
__device__ __forceinline__ void gload16(const void* g, void* l) {
  __builtin_amdgcn_global_load_lds(
      (const __attribute__((address_space(1))) unsigned int*)g,
      (__attribute__((address_space(3))) unsigned int*)l, 16, 0, 0);
}

// ---- fused prologue: convert | trig table | transpose wq | transpose wo ----
__global__ __launch_bounds__(256) void prologue_kernel(
    const float* __restrict__ x, unsigned short* __restrict__ xb,
    const float* __restrict__ freqs, float* __restrict__ cosT,
    float* __restrict__ sinT, const float* __restrict__ w_qkv,
    unsigned short* __restrict__ wqT, const float* __restrict__ w_out,
    unsigned short* __restrict__ woT) {
  __shared__ float tile[32][33];
  const int blk = blockIdx.x, tid = threadIdx.x;

  if (blk < 4096) {  // convert x (f32) -> xb (bf16), 4 elems/thread
    int i = (blk * 256 + tid) * 4;
    float4 v = *(const float4*)&x[i];
    ushort4 o;
    o.x = f2b(v.x); o.y = f2b(v.y); o.z = f2b(v.z); o.w = f2b(v.w);
    *(ushort4*)&xb[i] = o;
    return;
  }
  if (blk < 4608) {  // cos/sin tables (131072 elems)
    int i = (blk - 4096) * 256 + tid;
    float f = freqs[i];
    cosT[i] = cosf(f);
    sinT[i] = sinf(f);
    return;
  }
  // transpose [K][N] f32 -> [N][K] bf16
  const float* src;
  unsigned short* dst;
  int K, N, bx, by;
  if (blk < 7680) {
    src = w_qkv; dst = wqT; K = 1024; N = 3072;
    const int t = blk - 4608;
    bx = t % 96; by = t / 96;
  } else {
    src = w_out; dst = woT; K = 1024; N = 1024;
    const int t = blk - 7680;
    bx = t % 32; by = t / 32;
  }
  const int n0 = bx * 32, k0 = by * 32;
  const int c = tid & 31, r4 = tid >> 5;
#pragma unroll
  for (int p = 0; p < 4; ++p) {
    int r = r4 + p * 8;
    tile[r][c] = src[(size_t)(k0 + r) * N + n0 + c];
  }
  __syncthreads();
#pragma unroll
  for (int p = 0; p < 4; ++p) {
    int r = r4 + p * 8;
    dst[(size_t)(n0 + r) * K + k0 + c] = f2b(tile[c][r]);
  }
}

// ------ fused qkv GEMM + RoPE + layout (replaces gemm_wide + prep) ---------
// 128x192 tile, BK=32, 256 thr = 4 waves (2M x 2N), per-wave 64x96 (acc 4x6)
// with B-frag col mapping j*32 + wc*16 + fr (RoPE pairs thread-local).
// Ring of 4 LDS slots (20 KB) = 80 KB; counted vmcnt(10); ladder 10/5/0.
// Epilogue per 64-col head block jp: q -> RoPE*QSCALE -> Qb; k -> RoPE -> Kb;
// v -> LDS 64x66 bf16 tile (slot-0 region, safe) -> transposed+k-permuted
// ushort4 writes to Vtg (identical index map to the old prep_kernel).
__global__ __launch_bounds__(256, 2) void gemm_fused(
    const unsigned short* __restrict__ A, const unsigned short* __restrict__ BT,
    unsigned short* __restrict__ Qb, unsigned short* __restrict__ Kbp,
    unsigned short* __restrict__ Vtg, const float* __restrict__ cosT,
    const float* __restrict__ sinT) {
  extern __shared__ unsigned short L[];  // 4 slots x 10240 ushort = 80 KB
  const int K = 1024;
  const int tid = threadIdx.x, lane = tid & 63, w = tid >> 6;
  const int wr = w >> 1, wc = w & 1;
  const int fr = lane & 15, oct = lane >> 4;

  const int m0 = blockIdx.y * 128, n0 = blockIdx.x * 192;

  const int sr = tid >> 2;                                 // 0..63
  const int scol = ((tid & 3) ^ ((tid >> 3) & 3)) * 8;     // swizzled src col
  const size_t aR0 = (size_t)(m0 + sr) * K + scol;
  const size_t aR1 = (size_t)(m0 + 64 + sr) * K + scol;
  const size_t bR0 = (size_t)(n0 + sr) * K + scol;
  const size_t bR1 = (size_t)(n0 + 64 + sr) * K + scol;
  const size_t bR2 = (size_t)(n0 + 128 + sr) * K + scol;

  f32x4 acc[4][6] = {};
  const int T = K >> 5;

  for (int pt = 0; pt < 3; ++pt) {  // prologue: stage tiles 0,1,2
    unsigned short* Ln = &L[pt * 10240];
    const size_t gk = (size_t)pt * 32;
    gload16(&A[aR0 + gk], &Ln[tid * 8]);
    gload16(&A[aR1 + gk], &Ln[2048 + tid * 8]);
    gload16(&BT[bR0 + gk], &Ln[4096 + tid * 8]);
    gload16(&BT[bR1 + gk], &Ln[6144 + tid * 8]);
    gload16(&BT[bR2 + gk], &Ln[8192 + tid * 8]);
  }

  for (int t = 0; t < T; ++t) {
    if (t + 3 <= T) {
      asm volatile("s_waitcnt vmcnt(10)" ::: "memory");
    } else if (t + 2 == T) {
      asm volatile("s_waitcnt vmcnt(5)" ::: "memory");
    } else {
      asm volatile("s_waitcnt vmcnt(0)" ::: "memory");
    }
    __builtin_amdgcn_sched_barrier(0);
    __builtin_amdgcn_s_barrier();
    __builtin_amdgcn_sched_barrier(0);

    const unsigned short* Lb = &L[(t & 3) * 10240];
    unsigned short* Ln = &L[((t + 3) & 3) * 10240];
    const size_t gk = (size_t)(t + 3) * 32;
    const bool doStage = (t + 3 < T);

    bf16x8 af[4], bf[6];
#pragma unroll
    for (int i = 0; i < 4; ++i) {
      const int ra = wr * 64 + i * 16 + fr;
      af[i] = __builtin_bit_cast(
          bf16x8, *(const uint4*)&Lb[ra * 32 + ((oct ^ ((ra >> 1) & 3)) * 8)]);
    }
#pragma unroll
    for (int j = 0; j < 3; ++j) {
      const int rb = j * 32 + wc * 16 + fr;
      bf[j] = __builtin_bit_cast(
          bf16x8,
          *(const uint4*)&Lb[4096 + rb * 32 + ((oct ^ ((rb >> 1) & 3)) * 8)]);
    }
    if (doStage) {
      gload16(&A[aR0 + gk], &Ln[tid * 8]);
      gload16(&A[aR1 + gk], &Ln[2048 + tid * 8]);
      gload16(&BT[bR0 + gk], &Ln[4096 + tid * 8]);
    }
    __builtin_amdgcn_s_setprio(1);
#pragma unroll
    for (int i = 0; i < 4; ++i)
#pragma unroll
      for (int j = 0; j < 3; ++j)
        acc[i][j] = __builtin_amdgcn_mfma_f32_16x16x32_bf16(af[i], bf[j], acc[i][j], 0, 0, 0);
    __builtin_amdgcn_s_setprio(0);

#pragma unroll
    for (int j = 3; j < 6; ++j) {
      const int rb = j * 32 + wc * 16 + fr;
      bf[j] = __builtin_bit_cast(
          bf16x8,
          *(const uint4*)&Lb[4096 + rb * 32 + ((oct ^ ((rb >> 1) & 3)) * 8)]);
    }
    if (doStage) {
      gload16(&BT[bR1 + gk], &Ln[6144 + tid * 8]);
      gload16(&BT[bR2 + gk], &Ln[8192 + tid * 8]);
    }
    __builtin_amdgcn_s_setprio(1);
#pragma unroll
    for (int i = 0; i < 4; ++i)
#pragma unroll
      for (int j = 3; j < 6; ++j)
        acc[i][j] = __builtin_amdgcn_mfma_f32_16x16x32_bf16(af[i], bf[j], acc[i][j], 0, 0, 0);
    __builtin_amdgcn_s_setprio(0);
  }

  // ---- fused epilogue: RoPE q/k + transposed V, direct to Qb/Kb/Vtg ----
  const float QSCALE = 0.125f * 1.44269504f;
  unsigned short* vtile = L + wr * (64 * 66);  // per-wr-half staging (slot 0)
#pragma unroll
  for (int jp = 0; jp < 3; ++jp) {
    const int gbase = n0 + jp * 64;          // 64-aligned, part-uniform
    const int part = gbase >> 10;            // 0=q, 1=k, 2=v
    const int hh = (gbase & 1023) >> 6;      // head 0..15
    const int dlo = wc * 16 + fr;            // [0,32)
    if (part < 2) {
      unsigned short* dst = (part == 0) ? Qb : Kbp;
      const float scale = (part == 0) ? QSCALE : 1.0f;
#pragma unroll
      for (int i = 0; i < 4; ++i) {
#pragma unroll
        for (int r = 0; r < 4; ++r) {
          const int m = m0 + wr * 64 + i * 16 + oct * 4 + r;
          const int bb = m >> 11, s = m & 2047;
          const float lo = acc[i][2 * jp][r], hi = acc[i][2 * jp + 1][r];
          const float cl = cosT[s * 64 + dlo], sl = sinT[s * 64 + dlo];
          const float ch = cosT[s * 64 + 32 + dlo], sh = sinT[s * 64 + 32 + dlo];
          const size_t ob = ((size_t)(bb * 16 + hh) * 2048 + s) * 64;
          dst[ob + dlo] = f2b((lo * cl - hi * sl) * scale);
          dst[ob + 32 + dlo] = f2b((hi * ch + lo * sh) * scale);
        }
      }
    } else {
      __syncthreads();  // prior vtile reads (previous V jp) complete
#pragma unroll
      for (int i = 0; i < 4; ++i)
#pragma unroll
        for (int r = 0; r < 4; ++r) {
          const int s64 = i * 16 + oct * 4 + r;
          vtile[s64 * 66 + dlo] = f2b(acc[i][2 * jp][r]);
          vtile[s64 * 66 + 32 + dlo] = f2b(acc[i][2 * jp + 1][r]);
        }
      __syncthreads();
      // transposed + k-permuted write (prep's exact mapping)
      const int wrt = tid >> 7, t128 = tid & 127;
      const int d = t128 >> 1, q2h = t128 & 1;
      const unsigned short* tt = L + wrt * (64 * 66);
      const int mtile = m0 + wrt * 64;
      const int bb = mtile >> 11, sb = (mtile & 2047) >> 6;
      const size_t vb = (((size_t)(bb * 16 + hh) * 32 + sb) * 64 + d) * 64;
#pragma unroll
      for (int q2 = 0; q2 < 2; ++q2) {
        const int qq = q2h * 2 + q2;
#pragma unroll
        for (int g = 0; g < 4; ++g) {
          ushort4 u;
          u.x = tt[(qq * 16 + g * 4 + 0) * 66 + d];
          u.y = tt[(qq * 16 + g * 4 + 1) * 66 + d];
          u.z = tt[(qq * 16 + g * 4 + 2) * 66 + d];
          u.w = tt[(qq * 16 + g * 4 + 3) * 66 + d];
          *(ushort4*)&Vtg[vb + (qq >> 1) * 32 + g * 8 + (qq & 1) * 4] = u;
        }
      }
    }
  }
}

// ---------------- ring-buffered bf16 GEMM for out GEMM (f32 C) -------------
__global__ __launch_bounds__(256, 2) void gemm2_ring(const unsigned short* __restrict__ A,
                                                     const unsigned short* __restrict__ BT,
                                                     float* __restrict__ C,
                                                     int M, int N, int K) {
  extern __shared__ unsigned short L[];  // 4 slots x 6144 ushort = 48 KB
  const int tid = threadIdx.x, lane = tid & 63, w = tid >> 6;
  const int wr = w >> 1, wc = w & 1;
  const int fr = lane & 15, oct = lane >> 4;
  const int m0 = blockIdx.y * 128, n0 = blockIdx.x * 64;

  const int sr = tid >> 2;
  const int scol = ((tid & 3) ^ ((tid >> 3) & 3)) * 8;  // swizzled src col
  const size_t aR0 = (size_t)(m0 + sr) * K + scol;
  const size_t aR1 = (size_t)(m0 + 64 + sr) * K + scol;
  const size_t bR0 = (size_t)(n0 + sr) * K + scol;

  f32x4 acc[4][2] = {};
  const int T = K >> 5;

  for (int pt = 0; pt < 3; ++pt) {  // prologue: stage tiles 0,1,2
    unsigned short* Ln = &L[pt * 6144];
    const size_t gk = (size_t)pt * 32;
    gload16(&A[aR0 + gk], &Ln[tid * 8]);
    gload16(&A[aR1 + gk], &Ln[2048 + tid * 8]);
    gload16(&BT[bR0 + gk], &Ln[4096 + tid * 8]);
  }

  for (int t = 0; t < T; ++t) {
    if (t + 3 <= T) {
      asm volatile("s_waitcnt vmcnt(6)" ::: "memory");
    } else if (t + 2 == T) {
      asm volatile("s_waitcnt vmcnt(3)" ::: "memory");
    } else {
      asm volatile("s_waitcnt vmcnt(0)" ::: "memory");
    }
    __builtin_amdgcn_sched_barrier(0);
    __builtin_amdgcn_s_barrier();
    __builtin_amdgcn_sched_barrier(0);

    const unsigned short* Lb = &L[(t & 3) * 6144];
    unsigned short* Ln = &L[((t + 3) & 3) * 6144];
    const size_t gk = (size_t)(t + 3) * 32;
    const bool doStage = (t + 3 < T);

    bf16x8 af[4], bq[2];
#pragma unroll
    for (int i = 0; i < 4; ++i) {
      const int ra = wr * 64 + i * 16 + fr;
      af[i] = __builtin_bit_cast(
          bf16x8, *(const uint4*)&Lb[ra * 32 + ((oct ^ ((ra >> 1) & 3)) * 8)]);
    }
#pragma unroll
    for (int j = 0; j < 2; ++j) {
      const int rb = wc * 32 + j * 16 + fr;
      bq[j] = __builtin_bit_cast(
          bf16x8,
          *(const uint4*)&Lb[4096 + rb * 32 + ((oct ^ ((rb >> 1) & 3)) * 8)]);
    }
    if (doStage) {
      gload16(&A[aR0 + gk], &Ln[tid * 8]);
      gload16(&A[aR1 + gk], &Ln[2048 + tid * 8]);
      gload16(&BT[bR0 + gk], &Ln[4096 + tid * 8]);
    }
    __builtin_amdgcn_s_setprio(1);
#pragma unroll
    for (int i = 0; i < 4; ++i)
#pragma unroll
      for (int j = 0; j < 2; ++j)
        acc[i][j] = __builtin_amdgcn_mfma_f32_16x16x32_bf16(af[i], bq[j], acc[i][j], 0, 0, 0);
    __builtin_amdgcn_s_setprio(0);
  }

#pragma unroll
  for (int i = 0; i < 4; ++i)
#pragma unroll
    for (int j = 0; j < 2; ++j)
#pragma unroll
      for (int r = 0; r < 4; ++r)
        C[(size_t)(m0 + wr * 64 + i * 16 + oct * 4 + r) * N + n0 + wc * 32 +
          j * 16 + fr] = acc[i][j][r];
}

// --------------------------- MFMA flash attention ---------------------------
// (byte-exact r13 kernel: proven 41us, WRITE 8MB, VGPR 48)
__global__ __launch_bounds__(512, 4) void attn_mfma(const unsigned short* __restrict__ Qb,
                                                    const unsigned short* __restrict__ Kb,
                                                    const unsigned short* __restrict__ Vtg,
                                                    unsigned short* __restrict__ attnb) {
  extern __shared__ unsigned short KV[];  // [8][64][72]
  const int h = blockIdx.y, b = blockIdx.z;
  const int qt0 = blockIdx.x;   // 0..15
  const int qt1 = 31 - qt0;     // 16..31
  const int tid = threadIdx.x, lane = tid & 63, w = tid >> 6;
  const int fr = lane & 15, oct = lane >> 4;
  const int grp = w >> 2, wq = w & 3;
  const int nhA = 16 - qt0, nhB = 15 - qt0;

  const size_t bh = (size_t)(b * 16 + h);
  const unsigned short* Kbase = Kb + bh * 131072;
  const unsigned short* Vbase = Vtg + bh * 131072;

  const int qtP1 = grp ? qt1 : qt0;
  const unsigned short* Qp1 = Qb + (bh * 2048 + qtP1 * 64 + wq * 16 + fr) * 64;
  const bf16x8 qa0 = __builtin_bit_cast(bf16x8, *(const uint4*)(Qp1 + oct * 8));
  const bf16x8 qa1 = __builtin_bit_cast(bf16x8, *(const uint4*)(Qp1 + 32 + oct * 8));
  const unsigned short* Qp2 = Qb + (bh * 2048 + qt1 * 64 + wq * 16 + fr) * 64;
  const bf16x8 qb0 = __builtin_bit_cast(bf16x8, *(const uint4*)(Qp2 + oct * 8));
  const bf16x8 qb1 = __builtin_bit_cast(bf16x8, *(const uint4*)(Qp2 + 32 + oct * 8));

  float m_prev = -1e30f;
  f32x4 acc[4] = {};
  f32x4 accl = {};

  uint4 onesu;
  onesu.x = 0x3F803F80u; onesu.y = 0x3F803F80u;
  onesu.z = 0x3F803F80u; onesu.w = 0x3F803F80u;
  const bf16x8 onesf = __builtin_bit_cast(bf16x8, onesu);

  auto tile_step = [&](int buf, bf16x8 q0, bf16x8 q1, bool domask) {
    const unsigned short* Kbuf = &KV[buf * 4608];
    const unsigned short* Vbuf = &KV[(4 + buf) * 4608];
    f32x4 s4[4];
    __builtin_amdgcn_s_setprio(1);
#pragma unroll
    for (int t = 0; t < 4; ++t) {
      bf16x8 kf0 = __builtin_bit_cast(bf16x8, *(const uint4*)&Kbuf[(t * 16 + fr) * 72 + oct * 8]);
      bf16x8 kf1 = __builtin_bit_cast(bf16x8, *(const uint4*)&Kbuf[(t * 16 + fr) * 72 + 32 + oct * 8]);
      f32x4 s = {};
      s = __builtin_amdgcn_mfma_f32_16x16x32_bf16(kf0, q0, s, 0, 0, 0);
      s = __builtin_amdgcn_mfma_f32_16x16x32_bf16(kf1, q1, s, 0, 0, 0);
      s4[t] = s;
    }
    __builtin_amdgcn_s_setprio(0);
    if (domask) {
#pragma unroll
      for (int t = 0; t < 4; ++t)
#pragma unroll
        for (int r = 0; r < 4; ++r)
          if (t * 16 + oct * 4 + r > wq * 16 + fr) s4[t][r] = -1e30f;
    }

    float pm = -1e30f;
#pragma unroll
    for (int t = 0; t < 4; ++t)
#pragma unroll
      for (int r = 0; r < 4; ++r) pm = fmaxf(pm, s4[t][r]);
    const bool need = __any(pm - m_prev > 11.0f);
    if (need) {
      float pmf = fmaxf(pm, __shfl_xor(pm, 16));
      pmf = fmaxf(pmf, __shfl_xor(pmf, 32));
      float mnew = fmaxf(m_prev, pmf);
      float cf = __builtin_amdgcn_exp2f(m_prev - mnew);
      m_prev = mnew;
      float cfr[4];
#pragma unroll
      for (int r = 0; r < 4; ++r) cfr[r] = __shfl(cf, oct * 4 + r);
#pragma unroll
      for (int t2 = 0; t2 < 4; ++t2)
#pragma unroll
        for (int r = 0; r < 4; ++r) acc[t2][r] *= cfr[r];
#pragma unroll
      for (int r = 0; r < 4; ++r) accl[r] *= cfr[r];
    }
    const float mc = m_prev;
#pragma unroll
    for (int t = 0; t < 4; ++t)
#pragma unroll
      for (int r = 0; r < 4; ++r)
        s4[t][r] = __builtin_amdgcn_exp2f(s4[t][r] - mc);

    uint4 pw0, pw1;
    pw0.x = cvtpk(s4[0][0], s4[0][1]); pw0.y = cvtpk(s4[0][2], s4[0][3]);
    pw0.z = cvtpk(s4[1][0], s4[1][1]); pw0.w = cvtpk(s4[1][2], s4[1][3]);
    pw1.x = cvtpk(s4[2][0], s4[2][1]); pw1.y = cvtpk(s4[2][2], s4[2][3]);
    pw1.z = cvtpk(s4[3][0], s4[3][1]); pw1.w = cvtpk(s4[3][2], s4[3][3]);
    const bf16x8 pa0 = __builtin_bit_cast(bf16x8, pw0);
    const bf16x8 pa1 = __builtin_bit_cast(bf16x8, pw1);

    __builtin_amdgcn_s_setprio(1);
#pragma unroll
    for (int t2 = 0; t2 < 4; ++t2) {
      bf16x8 vf0 = __builtin_bit_cast(bf16x8, *(const uint4*)&Vbuf[(t2 * 16 + fr) * 72 + oct * 8]);
      bf16x8 vf1 = __builtin_bit_cast(bf16x8, *(const uint4*)&Vbuf[(t2 * 16 + fr) * 72 + 32 + oct * 8]);
      f32x4 a = acc[t2];
      a = __builtin_amdgcn_mfma_f32_16x16x32_bf16(pa0, vf0, a, 0, 0, 0);
      a = __builtin_amdgcn_mfma_f32_16x16x32_bf16(pa1, vf1, a, 0, 0, 0);
      acc[t2] = a;
    }
    {
      f32x4 a = accl;
      a = __builtin_amdgcn_mfma_f32_16x16x32_bf16(pa0, onesf, a, 0, 0, 0);
      a = __builtin_amdgcn_mfma_f32_16x16x32_bf16(pa1, onesf, a, 0, 0, 0);
      accl = a;
    }
    __builtin_amdgcn_s_setprio(0);
  };

  auto write_out = [&](int qtile) {
#pragma unroll
    for (int r = 0; r < 4; ++r) {
      float linv = 1.f / accl[r];
      size_t orow = (size_t)(b * 2048 + qtile * 64 + wq * 16 + oct * 4 + r);
#pragma unroll
      for (int t2 = 0; t2 < 4; ++t2)
        attnb[orow * 1024 + h * 64 + t2 * 16 + fr] = f2b(acc[t2][r] * linv);
    }
  };

  // ---- phase 1 staging (512 threads, 1 uint4 K + 1 uint4 V each) ----
  const int srow = tid >> 3, sc8 = (tid & 7) * 8;
  const unsigned short* kp1 = Kbase + srow * 64 + sc8;
  const unsigned short* vp1 = Vbase + srow * 64 + sc8;
  {
    uint4 kr = *(const uint4*)kp1;
    uint4 vr = *(const uint4*)vp1;
    *(uint4*)&KV[0 * 4608 + srow * 72 + sc8] = kr;
    *(uint4*)&KV[4 * 4608 + srow * 72 + sc8] = vr;
  }
  __syncthreads();

  for (int kb = 0; kb <= qt0; ++kb) {
    uint4 kr = *(const uint4*)(kp1 + (size_t)(kb + 1) * 4096);
    uint4 vr = *(const uint4*)(vp1 + (size_t)(kb + 1) * 4096);
    uint4 kr2, vr2;
    const bool extra = (kb == qt0) && (nhB > 0);
    if (extra) {  // pre-stage B's first phase-2 tile (17) into buf 2
      kr2 = *(const uint4*)(kp1 + (size_t)17 * 4096);
      vr2 = *(const uint4*)(vp1 + (size_t)17 * 4096);
    }
    tile_step(kb & 1, qa0, qa1, kb == qtP1);
    const int nb = (kb + 1) & 1;
    *(uint4*)&KV[nb * 4608 + srow * 72 + sc8] = kr;
    *(uint4*)&KV[(4 + nb) * 4608 + srow * 72 + sc8] = vr;
    if (extra) {
      *(uint4*)&KV[2 * 4608 + srow * 72 + sc8] = kr2;
      *(uint4*)&KV[6 * 4608 + srow * 72 + sc8] = vr2;
    }
    __syncthreads();
  }

  // group A: flush qt0 output, reset state for phase-2 partial
  if (grp == 0) {
    write_out(qt0);
    m_prev = -1e30f;
    f32x4 zz = {};
    accl = zz;
#pragma unroll
    for (int t2 = 0; t2 < 4; ++t2) acc[t2] = zz;
  }

  // ---- phase 2: A takes kb=qt0+1..16, B takes kb=17..qt1 ----
  const int t2id = tid & 255;
  const int sk2 = t2id >> 2, sc2 = (t2id & 3) * 16;
  const int cnt = grp ? nhB : nhA;
  for (int i = 0; i < nhA; ++i) {
    const int kbm = grp ? (17 + i) : (qt0 + 1 + i);
    const int buf = grp ? (2 + (i & 1)) : (kbm & 1);
    uint4 k0, k1, v0, v1;
    const bool pf = (i + 1 < cnt);
    if (pf) {
      const unsigned short* ks = Kbase + (size_t)((kbm + 1) * 64 + sk2) * 64 + sc2;
      const unsigned short* vs = Vbase + (size_t)((kbm + 1) * 64 + sk2) * 64 + sc2;
      k0 = *(const uint4*)ks; k1 = *(const uint4*)(ks + 8);
      v0 = *(const uint4*)vs; v1 = *(const uint4*)(vs + 8);
    }
    if (i < cnt) tile_step(buf, qb0, qb1, kbm == qt1);
    if (pf) {
      const int nb = grp ? (2 + ((i + 1) & 1)) : ((kbm + 1) & 1);
      *(uint4*)&KV[nb * 4608 + sk2 * 72 + sc2] = k0;
      *(uint4*)&KV[nb * 4608 + sk2 * 72 + sc2 + 8] = k1;
      *(uint4*)&KV[(4 + nb) * 4608 + sk2 * 72 + sc2] = v0;
      *(uint4*)&KV[(4 + nb) * 4608 + sk2 * 72 + sc2 + 8] = v1;
    }
    __syncthreads();
  }

  // ---- merge partials (B -> LDS overlay, A combines and writes qt1) ----
  float* MF = (float*)KV;  // overlays dead K/V buffers
  if (grp == 1) {
#pragma unroll
    for (int t2 = 0; t2 < 4; ++t2)
#pragma unroll
      for (int r = 0; r < 4; ++r)
        MF[(wq * 16 + oct * 4 + r) * 68 + t2 * 16 + fr] = acc[t2][r];
    if (fr == 0) {
#pragma unroll
      for (int r = 0; r < 4; ++r) MF[4352 + wq * 16 + oct * 4 + r] = accl[r];
    }
    if (oct == 0) MF[4416 + wq * 16 + fr] = m_prev;
  }
  __syncthreads();
  if (grp == 0) {
    float mB = MF[4416 + wq * 16 + fr];
    float mS = fmaxf(m_prev, mB);
    float fA = __builtin_amdgcn_exp2f(m_prev - mS);
    float fB = __builtin_amdgcn_exp2f(mB - mS);
    float fAr[4], fBr[4];
#pragma unroll
    for (int r = 0; r < 4; ++r) {
      fAr[r] = __shfl(fA, oct * 4 + r);
      fBr[r] = __shfl(fB, oct * 4 + r);
    }
#pragma unroll
    for (int r = 0; r < 4; ++r)
      accl[r] = accl[r] * fAr[r] + MF[4352 + wq * 16 + oct * 4 + r] * fBr[r];
#pragma unroll
    for (int t2 = 0; t2 < 4; ++t2)
#pragma unroll
      for (int r = 0; r < 4; ++r)
        acc[t2][r] = acc[t2][r] * fAr[r] +
                     MF[(wq * 16 + oct * 4 + r) * 68 + t2 * 16 + fr] * fBr[r];
    write_out(qt1);
  }
}

// ---------------------------------------------------------------------------
extern "C" void kernel_launch(void* const* d_in, const int* in_sizes, int n_in,
                              void* d_out, int out_size, void* d_ws, size_t ws_size,
                              hipStream_t stream) {
  const float* x     = (const float*)d_in[0];  // [2,2048,1024]
  const float* w_qkv = (const float*)d_in[1];  // [1024,3072]
  const float* w_out = (const float*)d_in[2];  // [1024,1024]
  const float* freqs = (const float*)d_in[3];  // [2048,64]
  float* out = (float*)d_out;

  char* ws = (char*)d_ws;
  unsigned short* Qb   = (unsigned short*)(ws + 25165824);  // 8388608
  unsigned short* Kb   = (unsigned short*)(ws + 33554432);  // 8388608
  unsigned short* Vtg  = (unsigned short*)(ws + 41943040);  // 8388608
  unsigned short* attnb= (unsigned short*)(ws + 50331648);  // 8388608
  unsigned short* wqT  = (unsigned short*)(ws + 58720256);  // 6291456
  unsigned short* woT  = (unsigned short*)(ws + 65011712);  // 2097152
  unsigned short* xb   = (unsigned short*)(ws + 67108864);  // 8388608
  float* cosT          = (float*)(ws + 75497472);           // 524288
  float* sinT          = (float*)(ws + 76021760);           // 524288
  // total ws use: 76546048 bytes (~73 MiB)

  (void)hipFuncSetAttribute((const void*)gemm_fused,
                            hipFuncAttributeMaxDynamicSharedMemorySize, 81920);
  (void)hipFuncSetAttribute((const void*)gemm2_ring,
                            hipFuncAttributeMaxDynamicSharedMemorySize, 49152);
  (void)hipFuncSetAttribute((const void*)attn_mfma,
                            hipFuncAttributeMaxDynamicSharedMemorySize, 73728);

  prologue_kernel<<<8704, 256, 0, stream>>>(x, xb, freqs, cosT, sinT, w_qkv,
                                            wqT, w_out, woT);
  gemm_fused<<<dim3(16, 32), 256, 81920, stream>>>(xb, wqT, Qb, Kb, Vtg, cosT,
                                                   sinT);
  attn_mfma<<<dim3(16, 16, 2), 512, 73728, stream>>>(Qb, Kb, Vtg, attnb);
  gemm2_ring<<<dim3(16, 32), 256, 49152, stream>>>(attnb, woT, out, 4096, 1024, 1024);
}

// Round 22
// 93.197 us; speedup vs baseline: 1.7252x; 1.0337x over previous
//
#include <hip/hip_runtime.h>

// ---------------------------------------------------------------------------
// Fused attention block: qkv GEMM+RoPE+layout -> causal SDPA (MFMA) -> out GEMM
// B=2 S=2048 D=1024 H=16 DH=64. bf16 MFMA everywhere.
// MFMA fragment mapping (verified r1-r13): A/B-frag outer=lane&15, k=oct*8+e;
// C/D row=oct*4+r, col=lane&15.
// r22: attn XCD-bijective block swizzle: all 16 q-tile blocks sharing one
//      (h,b)'s 256KB K/V working set land on ONE XCD (bid&7), so K/V is
//      fetched into one L2 instead of eight (attn FETCH was 77MB vs ~25MB
//      unique). Pure index remap; work uniform so no balance impact.
//      Everything else byte-identical to r21 (96.3us best).
// ---------------------------------------------------------------------------

typedef __bf16 bf16x8 __attribute__((ext_vector_type(8)));
typedef float f32x4 __attribute__((ext_vector_type(4)));

__device__ __forceinline__ unsigned short f2b(float f) {
  unsigned int u = __builtin_bit_cast(unsigned int, f);
  unsigned int lsb = (u >> 16) & 1u;
  u += 0x7fffu + lsb;  // round-to-nearest-even
  return (unsigned short)(u >> 16);
}
__device__ __forceinline__ float b2f(unsigned short h) {
  unsigned int u = ((unsigned int)h) << 16;
  return __builtin_bit_cast(float, u);
}
__device__ __forceinline__ unsigned int pk2(float a, float b) {
  return (unsigned int)f2b(a) | ((unsigned int)f2b(b) << 16);
}
__device__ __forceinline__ unsigned int cvtpk(float lo, float hi) {
  unsigned int r;
  asm("v_cvt_pk_bf16_f32 %0, %1, %2" : "=v"(r) : "v"(lo), "v"(hi));
  return r;
}
__device__ __forceinline__ void gload16(const void* g, void* l) {
  __builtin_amdgcn_global_load_lds(
      (const __attribute__((address_space(1))) unsigned int*)g,
      (__attribute__((address_space(3))) unsigned int*)l, 16, 0, 0);
}

// ---- fused prologue: convert | trig table | transpose wq | transpose wo ----
__global__ __launch_bounds__(256) void prologue_kernel(
    const float* __restrict__ x, unsigned short* __restrict__ xb,
    const float* __restrict__ freqs, float* __restrict__ cosT,
    float* __restrict__ sinT, const float* __restrict__ w_qkv,
    unsigned short* __restrict__ wqT, const float* __restrict__ w_out,
    unsigned short* __restrict__ woT) {
  __shared__ float tile[32][33];
  const int blk = blockIdx.x, tid = threadIdx.x;

  if (blk < 4096) {  // convert x (f32) -> xb (bf16), 4 elems/thread
    int i = (blk * 256 + tid) * 4;
    float4 v = *(const float4*)&x[i];
    ushort4 o;
    o.x = f2b(v.x); o.y = f2b(v.y); o.z = f2b(v.z); o.w = f2b(v.w);
    *(ushort4*)&xb[i] = o;
    return;
  }
  if (blk < 4608) {  // cos/sin tables (131072 elems)
    int i = (blk - 4096) * 256 + tid;
    float f = freqs[i];
    cosT[i] = cosf(f);
    sinT[i] = sinf(f);
    return;
  }
  // transpose [K][N] f32 -> [N][K] bf16
  const float* src;
  unsigned short* dst;
  int K, N, bx, by;
  if (blk < 7680) {
    src = w_qkv; dst = wqT; K = 1024; N = 3072;
    const int t = blk - 4608;
    bx = t % 96; by = t / 96;
  } else {
    src = w_out; dst = woT; K = 1024; N = 1024;
    const int t = blk - 7680;
    bx = t % 32; by = t / 32;
  }
  const int n0 = bx * 32, k0 = by * 32;
  const int c = tid & 31, r4 = tid >> 5;
#pragma unroll
  for (int p = 0; p < 4; ++p) {
    int r = r4 + p * 8;
    tile[r][c] = src[(size_t)(k0 + r) * N + n0 + c];
  }
  __syncthreads();
#pragma unroll
  for (int p = 0; p < 4; ++p) {
    int r = r4 + p * 8;
    dst[(size_t)(n0 + r) * K + k0 + c] = f2b(tile[c][r]);
  }
}

// ------ fused qkv GEMM + RoPE + layout (replaces gemm_wide + prep) ---------
__global__ __launch_bounds__(256, 2) void gemm_fused(
    const unsigned short* __restrict__ A, const unsigned short* __restrict__ BT,
    unsigned short* __restrict__ Qb, unsigned short* __restrict__ Kbp,
    unsigned short* __restrict__ Vtg, const float* __restrict__ cosT,
    const float* __restrict__ sinT) {
  extern __shared__ unsigned short L[];  // 4 slots x 10240 ushort = 80 KB
  const int K = 1024;
  const int tid = threadIdx.x, lane = tid & 63, w = tid >> 6;
  const int wr = w >> 1, wc = w & 1;
  const int fr = lane & 15, oct = lane >> 4;

  const int m0 = blockIdx.y * 128, n0 = blockIdx.x * 192;

  const int sr = tid >> 2;                                 // 0..63
  const int scol = ((tid & 3) ^ ((tid >> 3) & 3)) * 8;     // swizzled src col
  const size_t aR0 = (size_t)(m0 + sr) * K + scol;
  const size_t aR1 = (size_t)(m0 + 64 + sr) * K + scol;
  const size_t bR0 = (size_t)(n0 + sr) * K + scol;
  const size_t bR1 = (size_t)(n0 + 64 + sr) * K + scol;
  const size_t bR2 = (size_t)(n0 + 128 + sr) * K + scol;

  f32x4 acc[4][6] = {};
  const int T = K >> 5;

  for (int pt = 0; pt < 3; ++pt) {  // prologue: stage tiles 0,1,2
    unsigned short* Ln = &L[pt * 10240];
    const size_t gk = (size_t)pt * 32;
    gload16(&A[aR0 + gk], &Ln[tid * 8]);
    gload16(&A[aR1 + gk], &Ln[2048 + tid * 8]);
    gload16(&BT[bR0 + gk], &Ln[4096 + tid * 8]);
    gload16(&BT[bR1 + gk], &Ln[6144 + tid * 8]);
    gload16(&BT[bR2 + gk], &Ln[8192 + tid * 8]);
  }

  for (int t = 0; t < T; ++t) {
    if (t + 3 <= T) {
      asm volatile("s_waitcnt vmcnt(10)" ::: "memory");
    } else if (t + 2 == T) {
      asm volatile("s_waitcnt vmcnt(5)" ::: "memory");
    } else {
      asm volatile("s_waitcnt vmcnt(0)" ::: "memory");
    }
    __builtin_amdgcn_sched_barrier(0);
    __builtin_amdgcn_s_barrier();
    __builtin_amdgcn_sched_barrier(0);

    const unsigned short* Lb = &L[(t & 3) * 10240];
    unsigned short* Ln = &L[((t + 3) & 3) * 10240];
    const size_t gk = (size_t)(t + 3) * 32;
    const bool doStage = (t + 3 < T);

    bf16x8 af[4], bf[6];
#pragma unroll
    for (int i = 0; i < 4; ++i) {
      const int ra = wr * 64 + i * 16 + fr;
      af[i] = __builtin_bit_cast(
          bf16x8, *(const uint4*)&Lb[ra * 32 + ((oct ^ ((ra >> 1) & 3)) * 8)]);
    }
#pragma unroll
    for (int j = 0; j < 3; ++j) {
      const int rb = j * 32 + wc * 16 + fr;
      bf[j] = __builtin_bit_cast(
          bf16x8,
          *(const uint4*)&Lb[4096 + rb * 32 + ((oct ^ ((rb >> 1) & 3)) * 8)]);
    }
    if (doStage) {
      gload16(&A[aR0 + gk], &Ln[tid * 8]);
      gload16(&A[aR1 + gk], &Ln[2048 + tid * 8]);
      gload16(&BT[bR0 + gk], &Ln[4096 + tid * 8]);
    }
    __builtin_amdgcn_s_setprio(1);
#pragma unroll
    for (int i = 0; i < 4; ++i)
#pragma unroll
      for (int j = 0; j < 3; ++j)
        acc[i][j] = __builtin_amdgcn_mfma_f32_16x16x32_bf16(af[i], bf[j], acc[i][j], 0, 0, 0);
    __builtin_amdgcn_s_setprio(0);

#pragma unroll
    for (int j = 3; j < 6; ++j) {
      const int rb = j * 32 + wc * 16 + fr;
      bf[j] = __builtin_bit_cast(
          bf16x8,
          *(const uint4*)&Lb[4096 + rb * 32 + ((oct ^ ((rb >> 1) & 3)) * 8)]);
    }
    if (doStage) {
      gload16(&BT[bR1 + gk], &Ln[6144 + tid * 8]);
      gload16(&BT[bR2 + gk], &Ln[8192 + tid * 8]);
    }
    __builtin_amdgcn_s_setprio(1);
#pragma unroll
    for (int i = 0; i < 4; ++i)
#pragma unroll
      for (int j = 3; j < 6; ++j)
        acc[i][j] = __builtin_amdgcn_mfma_f32_16x16x32_bf16(af[i], bf[j], acc[i][j], 0, 0, 0);
    __builtin_amdgcn_s_setprio(0);
  }

  // ---- fused epilogue: RoPE q/k + transposed V, direct to Qb/Kb/Vtg ----
  const float QSCALE = 0.125f * 1.44269504f;
  unsigned short* vtile = L + wr * (64 * 66);  // per-wr-half staging (slot 0)
#pragma unroll
  for (int jp = 0; jp < 3; ++jp) {
    const int gbase = n0 + jp * 64;          // 64-aligned, part-uniform
    const int part = gbase >> 10;            // 0=q, 1=k, 2=v
    const int hh = (gbase & 1023) >> 6;      // head 0..15
    const int dlo = wc * 16 + fr;            // [0,32)
    if (part < 2) {
      unsigned short* dst = (part == 0) ? Qb : Kbp;
      const float scale = (part == 0) ? QSCALE : 1.0f;
#pragma unroll
      for (int i = 0; i < 4; ++i) {
#pragma unroll
        for (int r = 0; r < 4; ++r) {
          const int m = m0 + wr * 64 + i * 16 + oct * 4 + r;
          const int bb = m >> 11, s = m & 2047;
          const float lo = acc[i][2 * jp][r], hi = acc[i][2 * jp + 1][r];
          const float cl = cosT[s * 64 + dlo], sl = sinT[s * 64 + dlo];
          const float ch = cosT[s * 64 + 32 + dlo], sh = sinT[s * 64 + 32 + dlo];
          const size_t ob = ((size_t)(bb * 16 + hh) * 2048 + s) * 64;
          dst[ob + dlo] = f2b((lo * cl - hi * sl) * scale);
          dst[ob + 32 + dlo] = f2b((hi * ch + lo * sh) * scale);
        }
      }
    } else {
      __syncthreads();  // prior vtile reads (previous V jp) complete
#pragma unroll
      for (int i = 0; i < 4; ++i)
#pragma unroll
        for (int r = 0; r < 4; ++r) {
          const int s64 = i * 16 + oct * 4 + r;
          vtile[s64 * 66 + dlo] = f2b(acc[i][2 * jp][r]);
          vtile[s64 * 66 + 32 + dlo] = f2b(acc[i][2 * jp + 1][r]);
        }
      __syncthreads();
      // transposed + k-permuted write (prep's exact mapping)
      const int wrt = tid >> 7, t128 = tid & 127;
      const int d = t128 >> 1, q2h = t128 & 1;
      const unsigned short* tt = L + wrt * (64 * 66);
      const int mtile = m0 + wrt * 64;
      const int bb = mtile >> 11, sb = (mtile & 2047) >> 6;
      const size_t vb = (((size_t)(bb * 16 + hh) * 32 + sb) * 64 + d) * 64;
#pragma unroll
      for (int q2 = 0; q2 < 2; ++q2) {
        const int qq = q2h * 2 + q2;
#pragma unroll
        for (int g = 0; g < 4; ++g) {
          ushort4 u;
          u.x = tt[(qq * 16 + g * 4 + 0) * 66 + d];
          u.y = tt[(qq * 16 + g * 4 + 1) * 66 + d];
          u.z = tt[(qq * 16 + g * 4 + 2) * 66 + d];
          u.w = tt[(qq * 16 + g * 4 + 3) * 66 + d];
          *(ushort4*)&Vtg[vb + (qq >> 1) * 32 + g * 8 + (qq & 1) * 4] = u;
        }
      }
    }
  }
}

// ---------------- ring-buffered bf16 GEMM for out GEMM (f32 C) -------------
__global__ __launch_bounds__(256, 2) void gemm2_ring(const unsigned short* __restrict__ A,
                                                     const unsigned short* __restrict__ BT,
                                                     float* __restrict__ C,
                                                     int M, int N, int K) {
  extern __shared__ unsigned short L[];  // 4 slots x 6144 ushort = 48 KB
  const int tid = threadIdx.x, lane = tid & 63, w = tid >> 6;
  const int wr = w >> 1, wc = w & 1;
  const int fr = lane & 15, oct = lane >> 4;
  const int m0 = blockIdx.y * 128, n0 = blockIdx.x * 64;

  const int sr = tid >> 2;
  const int scol = ((tid & 3) ^ ((tid >> 3) & 3)) * 8;  // swizzled src col
  const size_t aR0 = (size_t)(m0 + sr) * K + scol;
  const size_t aR1 = (size_t)(m0 + 64 + sr) * K + scol;
  const size_t bR0 = (size_t)(n0 + sr) * K + scol;

  f32x4 acc[4][2] = {};
  const int T = K >> 5;

  for (int pt = 0; pt < 3; ++pt) {  // prologue: stage tiles 0,1,2
    unsigned short* Ln = &L[pt * 6144];
    const size_t gk = (size_t)pt * 32;
    gload16(&A[aR0 + gk], &Ln[tid * 8]);
    gload16(&A[aR1 + gk], &Ln[2048 + tid * 8]);
    gload16(&BT[bR0 + gk], &Ln[4096 + tid * 8]);
  }

  for (int t = 0; t < T; ++t) {
    if (t + 3 <= T) {
      asm volatile("s_waitcnt vmcnt(6)" ::: "memory");
    } else if (t + 2 == T) {
      asm volatile("s_waitcnt vmcnt(3)" ::: "memory");
    } else {
      asm volatile("s_waitcnt vmcnt(0)" ::: "memory");
    }
    __builtin_amdgcn_sched_barrier(0);
    __builtin_amdgcn_s_barrier();
    __builtin_amdgcn_sched_barrier(0);

    const unsigned short* Lb = &L[(t & 3) * 6144];
    unsigned short* Ln = &L[((t + 3) & 3) * 6144];
    const size_t gk = (size_t)(t + 3) * 32;
    const bool doStage = (t + 3 < T);

    bf16x8 af[4], bq[2];
#pragma unroll
    for (int i = 0; i < 4; ++i) {
      const int ra = wr * 64 + i * 16 + fr;
      af[i] = __builtin_bit_cast(
          bf16x8, *(const uint4*)&Lb[ra * 32 + ((oct ^ ((ra >> 1) & 3)) * 8)]);
    }
#pragma unroll
    for (int j = 0; j < 2; ++j) {
      const int rb = wc * 32 + j * 16 + fr;
      bq[j] = __builtin_bit_cast(
          bf16x8,
          *(const uint4*)&Lb[4096 + rb * 32 + ((oct ^ ((rb >> 1) & 3)) * 8)]);
    }
    if (doStage) {
      gload16(&A[aR0 + gk], &Ln[tid * 8]);
      gload16(&A[aR1 + gk], &Ln[2048 + tid * 8]);
      gload16(&BT[bR0 + gk], &Ln[4096 + tid * 8]);
    }
    __builtin_amdgcn_s_setprio(1);
#pragma unroll
    for (int i = 0; i < 4; ++i)
#pragma unroll
      for (int j = 0; j < 2; ++j)
        acc[i][j] = __builtin_amdgcn_mfma_f32_16x16x32_bf16(af[i], bq[j], acc[i][j], 0, 0, 0);
    __builtin_amdgcn_s_setprio(0);
  }

#pragma unroll
  for (int i = 0; i < 4; ++i)
#pragma unroll
    for (int j = 0; j < 2; ++j)
#pragma unroll
      for (int r = 0; r < 4; ++r)
        C[(size_t)(m0 + wr * 64 + i * 16 + oct * 4 + r) * N + n0 + wc * 32 +
          j * 16 + fr] = acc[i][j][r];
}

// --------------------------- MFMA flash attention ---------------------------
// (r13 kernel + XCD-bijective block swizzle; algorithm unchanged)
__global__ __launch_bounds__(512, 4) void attn_mfma(const unsigned short* __restrict__ Qb,
                                                    const unsigned short* __restrict__ Kb,
                                                    const unsigned short* __restrict__ Vtg,
                                                    unsigned short* __restrict__ attnb) {
  extern __shared__ unsigned short KV[];  // [8][64][72]
  // XCD-bijective swizzle: all 16 qt0-blocks of one (h,b) K/V group -> 1 XCD
  const int bid = blockIdx.x + 16 * (blockIdx.y + 16 * blockIdx.z);
  const int xcd = bid & 7, slot = bid >> 3;
  const int qt0 = slot & 15;           // 0..15
  const int gq = xcd + 8 * (slot >> 4);  // 0..31 (h,b group)
  const int h = gq & 15, b = gq >> 4;
  const int qt1 = 31 - qt0;            // 16..31
  const int tid = threadIdx.x, lane = tid & 63, w = tid >> 6;
  const int fr = lane & 15, oct = lane >> 4;
  const int grp = w >> 2, wq = w & 3;
  const int nhA = 16 - qt0, nhB = 15 - qt0;

  const size_t bh = (size_t)(b * 16 + h);
  const unsigned short* Kbase = Kb + bh * 131072;
  const unsigned short* Vbase = Vtg + bh * 131072;

  const int qtP1 = grp ? qt1 : qt0;
  const unsigned short* Qp1 = Qb + (bh * 2048 + qtP1 * 64 + wq * 16 + fr) * 64;
  const bf16x8 qa0 = __builtin_bit_cast(bf16x8, *(const uint4*)(Qp1 + oct * 8));
  const bf16x8 qa1 = __builtin_bit_cast(bf16x8, *(const uint4*)(Qp1 + 32 + oct * 8));
  const unsigned short* Qp2 = Qb + (bh * 2048 + qt1 * 64 + wq * 16 + fr) * 64;
  const bf16x8 qb0 = __builtin_bit_cast(bf16x8, *(const uint4*)(Qp2 + oct * 8));
  const bf16x8 qb1 = __builtin_bit_cast(bf16x8, *(const uint4*)(Qp2 + 32 + oct * 8));

  float m_prev = -1e30f;
  f32x4 acc[4] = {};
  f32x4 accl = {};

  uint4 onesu;
  onesu.x = 0x3F803F80u; onesu.y = 0x3F803F80u;
  onesu.z = 0x3F803F80u; onesu.w = 0x3F803F80u;
  const bf16x8 onesf = __builtin_bit_cast(bf16x8, onesu);

  auto tile_step = [&](int buf, bf16x8 q0, bf16x8 q1, bool domask) {
    const unsigned short* Kbuf = &KV[buf * 4608];
    const unsigned short* Vbuf = &KV[(4 + buf) * 4608];
    f32x4 s4[4];
    __builtin_amdgcn_s_setprio(1);
#pragma unroll
    for (int t = 0; t < 4; ++t) {
      bf16x8 kf0 = __builtin_bit_cast(bf16x8, *(const uint4*)&Kbuf[(t * 16 + fr) * 72 + oct * 8]);
      bf16x8 kf1 = __builtin_bit_cast(bf16x8, *(const uint4*)&Kbuf[(t * 16 + fr) * 72 + 32 + oct * 8]);
      f32x4 s = {};
      s = __builtin_amdgcn_mfma_f32_16x16x32_bf16(kf0, q0, s, 0, 0, 0);
      s = __builtin_amdgcn_mfma_f32_16x16x32_bf16(kf1, q1, s, 0, 0, 0);
      s4[t] = s;
    }
    __builtin_amdgcn_s_setprio(0);
    if (domask) {
#pragma unroll
      for (int t = 0; t < 4; ++t)
#pragma unroll
        for (int r = 0; r < 4; ++r)
          if (t * 16 + oct * 4 + r > wq * 16 + fr) s4[t][r] = -1e30f;
    }

    float pm = -1e30f;
#pragma unroll
    for (int t = 0; t < 4; ++t)
#pragma unroll
      for (int r = 0; r < 4; ++r) pm = fmaxf(pm, s4[t][r]);
    const bool need = __any(pm - m_prev > 11.0f);
    if (need) {
      float pmf = fmaxf(pm, __shfl_xor(pm, 16));
      pmf = fmaxf(pmf, __shfl_xor(pmf, 32));
      float mnew = fmaxf(m_prev, pmf);
      float cf = __builtin_amdgcn_exp2f(m_prev - mnew);
      m_prev = mnew;
      float cfr[4];
#pragma unroll
      for (int r = 0; r < 4; ++r) cfr[r] = __shfl(cf, oct * 4 + r);
#pragma unroll
      for (int t2 = 0; t2 < 4; ++t2)
#pragma unroll
        for (int r = 0; r < 4; ++r) acc[t2][r] *= cfr[r];
#pragma unroll
      for (int r = 0; r < 4; ++r) accl[r] *= cfr[r];
    }
    const float mc = m_prev;
#pragma unroll
    for (int t = 0; t < 4; ++t)
#pragma unroll
      for (int r = 0; r < 4; ++r)
        s4[t][r] = __builtin_amdgcn_exp2f(s4[t][r] - mc);

    uint4 pw0, pw1;
    pw0.x = cvtpk(s4[0][0], s4[0][1]); pw0.y = cvtpk(s4[0][2], s4[0][3]);
    pw0.z = cvtpk(s4[1][0], s4[1][1]); pw0.w = cvtpk(s4[1][2], s4[1][3]);
    pw1.x = cvtpk(s4[2][0], s4[2][1]); pw1.y = cvtpk(s4[2][2], s4[2][3]);
    pw1.z = cvtpk(s4[3][0], s4[3][1]); pw1.w = cvtpk(s4[3][2], s4[3][3]);
    const bf16x8 pa0 = __builtin_bit_cast(bf16x8, pw0);
    const bf16x8 pa1 = __builtin_bit_cast(bf16x8, pw1);

    __builtin_amdgcn_s_setprio(1);
#pragma unroll
    for (int t2 = 0; t2 < 4; ++t2) {
      bf16x8 vf0 = __builtin_bit_cast(bf16x8, *(const uint4*)&Vbuf[(t2 * 16 + fr) * 72 + oct * 8]);
      bf16x8 vf1 = __builtin_bit_cast(bf16x8, *(const uint4*)&Vbuf[(t2 * 16 + fr) * 72 + 32 + oct * 8]);
      f32x4 a = acc[t2];
      a = __builtin_amdgcn_mfma_f32_16x16x32_bf16(pa0, vf0, a, 0, 0, 0);
      a = __builtin_amdgcn_mfma_f32_16x16x32_bf16(pa1, vf1, a, 0, 0, 0);
      acc[t2] = a;
    }
    {
      f32x4 a = accl;
      a = __builtin_amdgcn_mfma_f32_16x16x32_bf16(pa0, onesf, a, 0, 0, 0);
      a = __builtin_amdgcn_mfma_f32_16x16x32_bf16(pa1, onesf, a, 0, 0, 0);
      accl = a;
    }
    __builtin_amdgcn_s_setprio(0);
  };

  auto write_out = [&](int qtile) {
#pragma unroll
    for (int r = 0; r < 4; ++r) {
      float linv = 1.f / accl[r];
      size_t orow = (size_t)(b * 2048 + qtile * 64 + wq * 16 + oct * 4 + r);
#pragma unroll
      for (int t2 = 0; t2 < 4; ++t2)
        attnb[orow * 1024 + h * 64 + t2 * 16 + fr] = f2b(acc[t2][r] * linv);
    }
  };

  // ---- phase 1 staging (512 threads, 1 uint4 K + 1 uint4 V each) ----
  const int srow = tid >> 3, sc8 = (tid & 7) * 8;
  const unsigned short* kp1 = Kbase + srow * 64 + sc8;
  const unsigned short* vp1 = Vbase + srow * 64 + sc8;
  {
    uint4 kr = *(const uint4*)kp1;
    uint4 vr = *(const uint4*)vp1;
    *(uint4*)&KV[0 * 4608 + srow * 72 + sc8] = kr;
    *(uint4*)&KV[4 * 4608 + srow * 72 + sc8] = vr;
  }
  __syncthreads();

  for (int kb = 0; kb <= qt0; ++kb) {
    uint4 kr = *(const uint4*)(kp1 + (size_t)(kb + 1) * 4096);
    uint4 vr = *(const uint4*)(vp1 + (size_t)(kb + 1) * 4096);
    uint4 kr2, vr2;
    const bool extra = (kb == qt0) && (nhB > 0);
    if (extra) {  // pre-stage B's first phase-2 tile (17) into buf 2
      kr2 = *(const uint4*)(kp1 + (size_t)17 * 4096);
      vr2 = *(const uint4*)(vp1 + (size_t)17 * 4096);
    }
    tile_step(kb & 1, qa0, qa1, kb == qtP1);
    const int nb = (kb + 1) & 1;
    *(uint4*)&KV[nb * 4608 + srow * 72 + sc8] = kr;
    *(uint4*)&KV[(4 + nb) * 4608 + srow * 72 + sc8] = vr;
    if (extra) {
      *(uint4*)&KV[2 * 4608 + srow * 72 + sc8] = kr2;
      *(uint4*)&KV[6 * 4608 + srow * 72 + sc8] = vr2;
    }
    __syncthreads();
  }

  // group A: flush qt0 output, reset state for phase-2 partial
  if (grp == 0) {
    write_out(qt0);
    m_prev = -1e30f;
    f32x4 zz = {};
    accl = zz;
#pragma unroll
    for (int t2 = 0; t2 < 4; ++t2) acc[t2] = zz;
  }

  // ---- phase 2: A takes kb=qt0+1..16, B takes kb=17..qt1 ----
  const int t2id = tid & 255;
  const int sk2 = t2id >> 2, sc2 = (t2id & 3) * 16;
  const int cnt = grp ? nhB : nhA;
  for (int i = 0; i < nhA; ++i) {
    const int kbm = grp ? (17 + i) : (qt0 + 1 + i);
    const int buf = grp ? (2 + (i & 1)) : (kbm & 1);
    uint4 k0, k1, v0, v1;
    const bool pf = (i + 1 < cnt);
    if (pf) {
      const unsigned short* ks = Kbase + (size_t)((kbm + 1) * 64 + sk2) * 64 + sc2;
      const unsigned short* vs = Vbase + (size_t)((kbm + 1) * 64 + sk2) * 64 + sc2;
      k0 = *(const uint4*)ks; k1 = *(const uint4*)(ks + 8);
      v0 = *(const uint4*)vs; v1 = *(const uint4*)(vs + 8);
    }
    if (i < cnt) tile_step(buf, qb0, qb1, kbm == qt1);
    if (pf) {
      const int nb = grp ? (2 + ((i + 1) & 1)) : ((kbm + 1) & 1);
      *(uint4*)&KV[nb * 4608 + sk2 * 72 + sc2] = k0;
      *(uint4*)&KV[nb * 4608 + sk2 * 72 + sc2 + 8] = k1;
      *(uint4*)&KV[(4 + nb) * 4608 + sk2 * 72 + sc2] = v0;
      *(uint4*)&KV[(4 + nb) * 4608 + sk2 * 72 + sc2 + 8] = v1;
    }
    __syncthreads();
  }

  // ---- merge partials (B -> LDS overlay, A combines and writes qt1) ----
  float* MF = (float*)KV;  // overlays dead K/V buffers
  if (grp == 1) {
#pragma unroll
    for (int t2 = 0; t2 < 4; ++t2)
#pragma unroll
      for (int r = 0; r < 4; ++r)
        MF[(wq * 16 + oct * 4 + r) * 68 + t2 * 16 + fr] = acc[t2][r];
    if (fr == 0) {
#pragma unroll
      for (int r = 0; r < 4; ++r) MF[4352 + wq * 16 + oct * 4 + r] = accl[r];
    }
    if (oct == 0) MF[4416 + wq * 16 + fr] = m_prev;
  }
  __syncthreads();
  if (grp == 0) {
    float mB = MF[4416 + wq * 16 + fr];
    float mS = fmaxf(m_prev, mB);
    float fA = __builtin_amdgcn_exp2f(m_prev - mS);
    float fB = __builtin_amdgcn_exp2f(mB - mS);
    float fAr[4], fBr[4];
#pragma unroll
    for (int r = 0; r < 4; ++r) {
      fAr[r] = __shfl(fA, oct * 4 + r);
      fBr[r] = __shfl(fB, oct * 4 + r);
    }
#pragma unroll
    for (int r = 0; r < 4; ++r)
      accl[r] = accl[r] * fAr[r] + MF[4352 + wq * 16 + oct * 4 + r] * fBr[r];
#pragma unroll
    for (int t2 = 0; t2 < 4; ++t2)
#pragma unroll
      for (int r = 0; r < 4; ++r)
        acc[t2][r] = acc[t2][r] * fAr[r] +
                     MF[(wq * 16 + oct * 4 + r) * 68 + t2 * 16 + fr] * fBr[r];
    write_out(qt1);
  }
}

// ---------------------------------------------------------------------------
extern "C" void kernel_launch(void* const* d_in, const int* in_sizes, int n_in,
                              void* d_out, int out_size, void* d_ws, size_t ws_size,
                              hipStream_t stream) {
  const float* x     = (const float*)d_in[0];  // [2,2048,1024]
  const float* w_qkv = (const float*)d_in[1];  // [1024,3072]
  const float* w_out = (const float*)d_in[2];  // [1024,1024]
  const float* freqs = (const float*)d_in[3];  // [2048,64]
  float* out = (float*)d_out;

  char* ws = (char*)d_ws;
  unsigned short* Qb   = (unsigned short*)(ws + 25165824);  // 8388608
  unsigned short* Kb   = (unsigned short*)(ws + 33554432);  // 8388608
  unsigned short* Vtg  = (unsigned short*)(ws + 41943040);  // 8388608
  unsigned short* attnb= (unsigned short*)(ws + 50331648);  // 8388608
  unsigned short* wqT  = (unsigned short*)(ws + 58720256);  // 6291456
  unsigned short* woT  = (unsigned short*)(ws + 65011712);  // 2097152
  unsigned short* xb   = (unsigned short*)(ws + 67108864);  // 8388608
  float* cosT          = (float*)(ws + 75497472);           // 524288
  float* sinT          = (float*)(ws + 76021760);           // 524288
  // total ws use: 76546048 bytes (~73 MiB)

  (void)hipFuncSetAttribute((const void*)gemm_fused,
                            hipFuncAttributeMaxDynamicSharedMemorySize, 81920);
  (void)hipFuncSetAttribute((const void*)gemm2_ring,
                            hipFuncAttributeMaxDynamicSharedMemorySize, 49152);
  (void)hipFuncSetAttribute((const void*)attn_mfma,
                            hipFuncAttributeMaxDynamicSharedMemorySize, 73728);

  prologue_kernel<<<8704, 256, 0, stream>>>(x, xb, freqs, cosT, sinT, w_qkv,
                                            wqT, w_out, woT);
  gemm_fused<<<dim3(16, 32), 256, 81920, stream>>>(xb, wqT, Qb, Kb, Vtg, cosT,
                                                   sinT);
  attn_mfma<<<dim3(16, 16, 2), 512, 73728, stream>>>(Qb, Kb, Vtg, attnb);
  gemm2_ring<<<dim3(16, 32), 256, 49152, stream>>>(attnb, woT, out, 4096, 1024, 1024);
}